// Round 3
// baseline (1886.537 us; speedup 1.0000x reference)
//
#include <hip/hip_runtime.h>
#include <cmath>

#define T_SEQ 2048
#define NH    16
#define HD    64
#define DM    1024
#define BATCH 4

typedef __attribute__((ext_vector_type(8))) short bf16x8;
typedef __attribute__((ext_vector_type(4))) float f32x4;
typedef unsigned short ushort_t;

// round-to-nearest-even fp32 -> bf16 bits
__device__ __forceinline__ unsigned short f2bf(float x) {
    union { float f; unsigned u; } v; v.f = x;
    unsigned r = v.u + 0x7fffu + ((v.u >> 16) & 1u);
    return (unsigned short)(r >> 16);
}
__device__ __forceinline__ float bf2f(unsigned short h) {
    union { unsigned u; float f; } v; v.u = ((unsigned)h) << 16;
    return v.f;
}
__device__ __forceinline__ unsigned fbits(float x) {
    union { float f; unsigned u; } v; v.f = x; return v.u;
}
__device__ __forceinline__ float bitsf(unsigned x) {
    union { unsigned u; float f; } v; v.u = x; return v.f;
}

// -------------------------------------------------------------------------
// Kernel 1: mask prep (unchanged, correct).
// -------------------------------------------------------------------------
__global__ void maskprep_kernel(const int* __restrict__ pad, float* __restrict__ valid)
{
    __shared__ int sall[256];
    const int b = blockIdx.x;
    const int t = threadIdx.x;
    int allp = 1;
    for (int i = t; i < T_SEQ; i += 256) allp &= (pad[b*T_SEQ + i] != 0) ? 1 : 0;
    sall[t] = allp;
    __syncthreads();
    for (int s = 128; s > 0; s >>= 1) {
        if (t < s) sall[t] &= sall[t + s];
        __syncthreads();
    }
    const int ap = sall[0];
    for (int i = t; i < T_SEQ; i += 256) {
        const int p = (pad[b*T_SEQ + i] != 0) ? 1 : 0;
        valid[b*T_SEQ + i] = (p && !ap) ? 0.0f : 1.0f;
    }
}

// -------------------------------------------------------------------------
// Kernel 2/4: fp32 SGEMM (unchanged, correct). EPI=1 emits bf16 hi/lo
// Q/K [bh][t][64] (Q pre-scaled 0.125, RoPE'd) and V transposed [bh][d][t].
// -------------------------------------------------------------------------
template<int EPI>
__global__ __launch_bounds__(256, 2)
void sgemm_kernel(const float* __restrict__ A, const float* __restrict__ B,
                  const float* __restrict__ bias,
                  float* __restrict__ O0,
                  ushort_t* __restrict__ Qhi, ushort_t* __restrict__ Qlo,
                  ushort_t* __restrict__ Khi, ushort_t* __restrict__ Klo,
                  ushort_t* __restrict__ Vthi, ushort_t* __restrict__ Vtlo,
                  int M, int N, int K)
{
    __shared__ float As[16][132];
    __shared__ float Bs[16][132];
    const int tid = threadIdx.x;
    const int tx  = tid & 15;
    const int ty  = tid >> 4;
    const int m0  = blockIdx.y * 128;
    const int n0  = blockIdx.x * 128;

    float acc[8][8];
#pragma unroll
    for (int i = 0; i < 8; ++i)
#pragma unroll
        for (int j = 0; j < 8; ++j) acc[i][j] = 0.0f;

    for (int kk = 0; kk < K; kk += 16) {
        __syncthreads();
#pragma unroll
        for (int p = 0; p < 2; ++p) {
            const int idx = tid + p * 256;
            const int m   = idx >> 2;
            const int kg  = (idx & 3) * 4;
            const float4 a = *(const float4*)&A[(size_t)(m0 + m) * K + kk + kg];
            As[kg+0][m] = a.x; As[kg+1][m] = a.y; As[kg+2][m] = a.z; As[kg+3][m] = a.w;
        }
#pragma unroll
        for (int p = 0; p < 2; ++p) {
            const int idx = tid + p * 256;
            const int kr  = idx >> 5;
            const int c   = (idx & 31) * 4;
            *(float4*)&Bs[kr][c] = *(const float4*)&B[(size_t)(kk + kr) * N + n0 + c];
        }
        __syncthreads();
#pragma unroll
        for (int k = 0; k < 16; ++k) {
            float a[8], b[8];
            *(float4*)&a[0] = *(const float4*)&As[k][ty*4];
            *(float4*)&a[4] = *(const float4*)&As[k][64 + ty*4];
            *(float4*)&b[0] = *(const float4*)&Bs[k][tx*4];
            *(float4*)&b[4] = *(const float4*)&Bs[k][64 + tx*4];
#pragma unroll
            for (int i = 0; i < 8; ++i)
#pragma unroll
                for (int j = 0; j < 8; ++j)
                    acc[i][j] = fmaf(a[i], b[j], acc[i][j]);
        }
    }

#pragma unroll
    for (int i = 0; i < 8; ++i) {
        const int m = m0 + ((i < 4) ? (ty*4 + i) : (64 + ty*4 + i - 4));
#pragma unroll
        for (int g = 0; g < 2; ++g) {
            const int n = n0 + g*64 + tx*4;
            float v[4];
#pragma unroll
            for (int j = 0; j < 4; ++j) v[j] = acc[i][g*4 + j] + bias[n + j];
            if (EPI == 0) {
                *(float4*)&O0[(size_t)m * N + n] = make_float4(v[0], v[1], v[2], v[3]);
            } else {
                const int b     = m >> 11;
                const int t     = m & 2047;
                const int which = n >> 10;          // 0=q 1=k 2=v
                const int w     = n & 1023;
                const int h     = w >> 6;
                const int d     = w & 63;
                const int bh    = b*NH + h;
                if (which < 2) {
                    const float fi = (float)(d >> 1);
                    const float tf = (float)t;
                    const float ang0 = tf * expf(fi * -0.28782313662425575f);
                    const float ang1 = tf * expf((fi + 1.0f) * -0.28782313662425575f);
                    const float s0 = sinf(ang0), c0 = cosf(ang0);
                    const float s1 = sinf(ang1), c1 = cosf(ang1);
                    const float e0 = v[0], od0 = v[1], e1 = v[2], od1 = v[3];
                    v[0] = e0*c0 - od0*s0;
                    v[1] = e0*s0 + od0*c0;
                    v[2] = e1*c1 - od1*s1;
                    v[3] = e1*s1 + od1*c1;
                    if (which == 0) {
#pragma unroll
                        for (int j = 0; j < 4; ++j) v[j] *= 0.125f;
                    }
                    ushort_t hi[4], lo[4];
#pragma unroll
                    for (int j = 0; j < 4; ++j) {
                        hi[j] = f2bf(v[j]);
                        lo[j] = f2bf(v[j] - bf2f(hi[j]));
                    }
                    ushort_t* dh = (which == 0) ? Qhi : Khi;
                    ushort_t* dl = (which == 0) ? Qlo : Klo;
                    const size_t off = ((((size_t)bh)*T_SEQ + t) << 6) + d;
                    *(short4*)&dh[off] = make_short4(hi[0], hi[1], hi[2], hi[3]);
                    *(short4*)&dl[off] = make_short4(lo[0], lo[1], lo[2], lo[3]);
                } else {
#pragma unroll
                    for (int j = 0; j < 4; ++j) {
                        const ushort_t hi = f2bf(v[j]);
                        const size_t off = (((size_t)bh)*HD + d + j)*T_SEQ + t;
                        Vthi[off] = hi;
                        Vtlo[off] = f2bf(v[j] - bf2f(hi));
                    }
                }
            }
        }
    }
}

// -------------------------------------------------------------------------
// Kernel 3: flash attention, split-bf16 MFMA, explicitly software-pipelined.
// 1-D grid 2048; block id remapped so all 32 q-tiles of one bh sit on one
// XCD (id%8): its K/V kt-tile is fetched once from L3, then L2-hits for the
// other 31 blocks. Per kt the load phases are issued ahead of the compute
// phase that hides them:
//   [kl loads] [S-hi MFMA] [vh loads] [S-lo MFMA] [softmax] [vl loads]
//   [P transpose/split] [kh(kt+1) loads] [PV MFMA]
// No __syncthreads in the loop; P transpose via wave-private LDS slab.
// -------------------------------------------------------------------------
__global__ __launch_bounds__(256, 4)
void attn_mfma_kernel(const ushort_t* __restrict__ Qhi, const ushort_t* __restrict__ Qlo,
                      const ushort_t* __restrict__ Khi, const ushort_t* __restrict__ Klo,
                      const ushort_t* __restrict__ Vthi, const ushort_t* __restrict__ Vtlo,
                      const float* __restrict__ valid, float* __restrict__ O)
{
    __shared__ float Pb[4][16][68];

    const int tid  = threadIdx.x;
    const int w    = tid >> 6;
    const int ln   = tid & 63;
    const int lx   = ln & 15;
    const int quad = ln >> 4;

    // XCD-aware remap: bh = 8*(id>>8) + (id&7), qt = (id>>3)&31.
    const int id = blockIdx.x;
    const int qt = (id >> 3) & 31;
    const int bh = ((id >> 8) << 3) | (id & 7);
    const int b  = bh >> 4;
    const int h  = bh & 15;
    const int qrow0 = qt*64 + w*16;

    // persistent Q A-fragments
    bf16x8 qh[2], ql[2];
    {
        const size_t qoff = (((size_t)bh)*T_SEQ + qrow0 + lx)*HD + quad*8;
        qh[0] = *(const bf16x8*)&Qhi[qoff];
        qh[1] = *(const bf16x8*)&Qhi[qoff + 32];
        ql[0] = *(const bf16x8*)&Qlo[qoff];
        ql[1] = *(const bf16x8*)&Qlo[qoff + 32];
    }

    // per-lane nt-tile base pointers (loop-invariant)
    const ushort_t* kh_nt[4];
    const ushort_t* kl_nt[4];
    const ushort_t* vh_nt[4];
    const ushort_t* vl_nt[4];
#pragma unroll
    for (int nt = 0; nt < 4; ++nt) {
        const size_t kroff = (((size_t)bh)*T_SEQ + nt*16 + lx)*HD + quad*8;
        kh_nt[nt] = Khi + kroff;
        kl_nt[nt] = Klo + kroff;
        const size_t vroff = (((size_t)bh)*HD + nt*16 + lx)*T_SEQ + quad*8;
        vh_nt[nt] = Vthi + vroff;
        vl_nt[nt] = Vtlo + vroff;
    }
    const float* vrow = valid + (size_t)b*T_SEQ + lx;

    f32x4 o[4];
#pragma unroll
    for (int nt = 0; nt < 4; ++nt) o[nt] = (f32x4){0.f, 0.f, 0.f, 0.f};
    float mrow[4] = {-INFINITY, -INFINITY, -INFINITY, -INFINITY};
    float lrow[4] = {0.f, 0.f, 0.f, 0.f};

    // prefetch K-hi fragments for kt=0
    bf16x8 khf[8];
#pragma unroll
    for (int nt = 0; nt < 4; ++nt) {
        khf[2*nt]   = *(const bf16x8*)(kh_nt[nt]);
        khf[2*nt+1] = *(const bf16x8*)(kh_nt[nt] + 32);
    }

    for (int kt = 0; kt < T_SEQ/64; ++kt) {
        const int koff = kt * 64 * HD;   // element offset into K arrays
        const int voff = kt * 64;        // element offset into Vt arrays

        // ---- issue mask + K-lo loads up front ----
        float mk[4];
#pragma unroll
        for (int nt = 0; nt < 4; ++nt) mk[nt] = vrow[kt*64 + nt*16];
        bf16x8 klf[8];
#pragma unroll
        for (int nt = 0; nt < 4; ++nt) {
            klf[2*nt]   = *(const bf16x8*)(kl_nt[nt] + koff);
            klf[2*nt+1] = *(const bf16x8*)(kl_nt[nt] + koff + 32);
        }

        // ---- S hi-terms (khf prefetched last iteration) ----
        f32x4 s[4];
#pragma unroll
        for (int nt = 0; nt < 4; ++nt) {
            s[nt] = (f32x4){0.f, 0.f, 0.f, 0.f};
            s[nt] = __builtin_amdgcn_mfma_f32_16x16x32_bf16(qh[0], khf[2*nt],   s[nt], 0, 0, 0);
            s[nt] = __builtin_amdgcn_mfma_f32_16x16x32_bf16(qh[1], khf[2*nt+1], s[nt], 0, 0, 0);
            s[nt] = __builtin_amdgcn_mfma_f32_16x16x32_bf16(ql[0], khf[2*nt],   s[nt], 0, 0, 0);
            s[nt] = __builtin_amdgcn_mfma_f32_16x16x32_bf16(ql[1], khf[2*nt+1], s[nt], 0, 0, 0);
        }

        // ---- issue V-hi loads (consumed after softmax) ----
        bf16x8 vhf[8];
#pragma unroll
        for (int nt = 0; nt < 4; ++nt) {
            vhf[2*nt]   = *(const bf16x8*)(vh_nt[nt] + voff);
            vhf[2*nt+1] = *(const bf16x8*)(vh_nt[nt] + voff + 32);
        }

        // ---- S lo-terms ----
#pragma unroll
        for (int nt = 0; nt < 4; ++nt) {
            s[nt] = __builtin_amdgcn_mfma_f32_16x16x32_bf16(qh[0], klf[2*nt],   s[nt], 0, 0, 0);
            s[nt] = __builtin_amdgcn_mfma_f32_16x16x32_bf16(qh[1], klf[2*nt+1], s[nt], 0, 0, 0);
        }

        // ---- mask ----
#pragma unroll
        for (int nt = 0; nt < 4; ++nt) {
            const bool ok = mk[nt] > 0.5f;
#pragma unroll
            for (int r = 0; r < 4; ++r) s[nt][r] = ok ? s[nt][r] : -1e30f;
        }

        // ---- online softmax ----
        float alpha[4], mnew[4];
#pragma unroll
        for (int r = 0; r < 4; ++r) {
            float mt = fmaxf(fmaxf(s[0][r], s[1][r]), fmaxf(s[2][r], s[3][r]));
            mt = fmaxf(mt, __shfl_xor(mt, 1));
            mt = fmaxf(mt, __shfl_xor(mt, 2));
            mt = fmaxf(mt, __shfl_xor(mt, 4));
            mt = fmaxf(mt, __shfl_xor(mt, 8));
            mnew[r]  = fmaxf(mrow[r], mt);
            alpha[r] = __expf(mrow[r] - mnew[r]);
            mrow[r]  = mnew[r];
        }
        float p[4][4];
#pragma unroll
        for (int r = 0; r < 4; ++r) {
            float lt = 0.f;
#pragma unroll
            for (int nt = 0; nt < 4; ++nt) { p[nt][r] = __expf(s[nt][r] - mnew[r]); lt += p[nt][r]; }
            lt += __shfl_xor(lt, 1);
            lt += __shfl_xor(lt, 2);
            lt += __shfl_xor(lt, 4);
            lt += __shfl_xor(lt, 8);
            lrow[r] = lrow[r]*alpha[r] + lt;
#pragma unroll
            for (int nt = 0; nt < 4; ++nt) o[nt][r] *= alpha[r];
        }

        // ---- issue V-lo loads ----
        bf16x8 vlf[8];
#pragma unroll
        for (int nt = 0; nt < 4; ++nt) {
            vlf[2*nt]   = *(const bf16x8*)(vl_nt[nt] + voff);
            vlf[2*nt+1] = *(const bf16x8*)(vl_nt[nt] + voff + 32);
        }

        // ---- P: C-layout -> A-layout via wave-private LDS; cheap trunc split ----
#pragma unroll
        for (int nt = 0; nt < 4; ++nt)
#pragma unroll
            for (int r = 0; r < 4; ++r)
                Pb[w][quad*4 + r][nt*16 + lx] = p[nt][r];

        bf16x8 ph[2], pl[2];
#pragma unroll
        for (int ks = 0; ks < 2; ++ks) {
            float pv[8];
            *(f32x4*)&pv[0] = *(const f32x4*)&Pb[w][lx][ks*32 + quad*8];
            *(f32x4*)&pv[4] = *(const f32x4*)&Pb[w][lx][ks*32 + quad*8 + 4];
#pragma unroll
            for (int j = 0; j < 8; ++j) {
                const unsigned ub = fbits(pv[j]);
                ph[ks][j] = (short)(ub >> 16);                       // trunc hi
                const float lof = pv[j] - bitsf(ub & 0xffff0000u);   // exact remainder
                pl[ks][j] = (short)(fbits(lof) >> 16);               // trunc lo
            }
        }

        // ---- prefetch K-hi for kt+1 (covered by PV MFMAs) ----
        {
            const int koff2 = (kt+1 < T_SEQ/64) ? (kt+1)*64*HD : koff;
#pragma unroll
            for (int nt = 0; nt < 4; ++nt) {
                khf[2*nt]   = *(const bf16x8*)(kh_nt[nt] + koff2);
                khf[2*nt+1] = *(const bf16x8*)(kh_nt[nt] + koff2 + 32);
            }
        }

        // ---- O += P V ----
#pragma unroll
        for (int nt = 0; nt < 4; ++nt) {
            o[nt] = __builtin_amdgcn_mfma_f32_16x16x32_bf16(ph[0], vhf[2*nt],   o[nt], 0, 0, 0);
            o[nt] = __builtin_amdgcn_mfma_f32_16x16x32_bf16(ph[1], vhf[2*nt+1], o[nt], 0, 0, 0);
            o[nt] = __builtin_amdgcn_mfma_f32_16x16x32_bf16(pl[0], vhf[2*nt],   o[nt], 0, 0, 0);
            o[nt] = __builtin_amdgcn_mfma_f32_16x16x32_bf16(pl[1], vhf[2*nt+1], o[nt], 0, 0, 0);
            o[nt] = __builtin_amdgcn_mfma_f32_16x16x32_bf16(ph[0], vlf[2*nt],   o[nt], 0, 0, 0);
            o[nt] = __builtin_amdgcn_mfma_f32_16x16x32_bf16(ph[1], vlf[2*nt+1], o[nt], 0, 0, 0);
        }
    }

    // ---- normalize + store AO[b][t][h*64+dv] ----
    float inv[4];
#pragma unroll
    for (int r = 0; r < 4; ++r) inv[r] = 1.0f / lrow[r];
#pragma unroll
    for (int nt = 0; nt < 4; ++nt)
#pragma unroll
        for (int r = 0; r < 4; ++r) {
            const int t = qrow0 + quad*4 + r;
            O[(((size_t)b)*T_SEQ + t)*DM + h*HD + nt*16 + lx] = o[nt][r] * inv[r];
        }
}

// -------------------------------------------------------------------------
// Workspace layout (unchanged):
//   AO [4][2048][1024] f32 | MSK [4][2048] f32 |
//   Qhi,Qlo,Khi,Klo [64][2048][64] u16 | Vthi,Vtlo [64][64][2048] u16
// -------------------------------------------------------------------------
extern "C" void kernel_launch(void* const* d_in, const int* in_sizes, int n_in,
                              void* d_out, int out_size, void* d_ws, size_t ws_size,
                              hipStream_t stream)
{
    const float* tokens = (const float*)d_in[0];
    const int*   pad    = (const int*)d_in[1];
    const float* Wqkv   = (const float*)d_in[2];
    const float* bqkv   = (const float*)d_in[3];
    const float* Wout   = (const float*)d_in[4];
    const float* bout   = (const float*)d_in[5];
    float* out = (float*)d_out;

    const size_t SZ = (size_t)8388608;
    float* AO  = (float*)d_ws;
    float* MSK = AO + SZ;
    ushort_t* U = (ushort_t*)(MSK + 8192);
    ushort_t* Qhi  = U;
    ushort_t* Qlo  = U + SZ;
    ushort_t* Khi  = U + 2*SZ;
    ushort_t* Klo  = U + 3*SZ;
    ushort_t* Vthi = U + 4*SZ;
    ushort_t* Vtlo = U + 5*SZ;

    maskprep_kernel<<<dim3(BATCH), dim3(256), 0, stream>>>(pad, MSK);
    sgemm_kernel<1><<<dim3(24, 64), dim3(256), 0, stream>>>(
        tokens, Wqkv, bqkv, nullptr, Qhi, Qlo, Khi, Klo, Vthi, Vtlo,
        BATCH*T_SEQ, 3*DM, DM);
    attn_mfma_kernel<<<dim3(2048), dim3(256), 0, stream>>>(
        Qhi, Qlo, Khi, Klo, Vthi, Vtlo, MSK, AO);
    sgemm_kernel<0><<<dim3(8, 64), dim3(256), 0, stream>>>(
        AO, Wout, bout, out, nullptr, nullptr, nullptr, nullptr, nullptr, nullptr,
        BATCH*T_SEQ, DM, DM);
}

// Round 4
// 1251.924 us; speedup vs baseline: 1.5069x; 1.5069x over previous
//
#include <hip/hip_runtime.h>
#include <cmath>

#define T_SEQ 2048
#define NH    16
#define HD    64
#define DM    1024
#define BATCH 4

typedef __attribute__((ext_vector_type(8))) short bf16x8;
typedef __attribute__((ext_vector_type(4))) float f32x4;
typedef unsigned short ushort_t;

// round-to-nearest-even fp32 -> bf16 bits
__device__ __forceinline__ unsigned short f2bf(float x) {
    union { float f; unsigned u; } v; v.f = x;
    unsigned r = v.u + 0x7fffu + ((v.u >> 16) & 1u);
    return (unsigned short)(r >> 16);
}
__device__ __forceinline__ float bf2f(unsigned short h) {
    union { unsigned u; float f; } v; v.u = ((unsigned)h) << 16;
    return v.f;
}
__device__ __forceinline__ unsigned fbits(float x) {
    union { float f; unsigned u; } v; v.f = x; return v.u;
}
__device__ __forceinline__ float bitsf(unsigned x) {
    union { unsigned u; float f; } v; v.u = x; return v.f;
}

// -------------------------------------------------------------------------
// Kernel 1: mask prep (unchanged, correct).
// -------------------------------------------------------------------------
__global__ void maskprep_kernel(const int* __restrict__ pad, float* __restrict__ valid)
{
    __shared__ int sall[256];
    const int b = blockIdx.x;
    const int t = threadIdx.x;
    int allp = 1;
    for (int i = t; i < T_SEQ; i += 256) allp &= (pad[b*T_SEQ + i] != 0) ? 1 : 0;
    sall[t] = allp;
    __syncthreads();
    for (int s = 128; s > 0; s >>= 1) {
        if (t < s) sall[t] &= sall[t + s];
        __syncthreads();
    }
    const int ap = sall[0];
    for (int i = t; i < T_SEQ; i += 256) {
        const int p = (pad[b*T_SEQ + i] != 0) ? 1 : 0;
        valid[b*T_SEQ + i] = (p && !ap) ? 0.0f : 1.0f;
    }
}

// -------------------------------------------------------------------------
// Kernel 2/4: fp32 SGEMM (unchanged, correct). EPI=1 emits bf16 hi/lo
// Q/K [bh][t][64] (Q pre-scaled 0.125, RoPE'd) and V transposed [bh][d][t].
// -------------------------------------------------------------------------
template<int EPI>
__global__ __launch_bounds__(256, 2)
void sgemm_kernel(const float* __restrict__ A, const float* __restrict__ B,
                  const float* __restrict__ bias,
                  float* __restrict__ O0,
                  ushort_t* __restrict__ Qhi, ushort_t* __restrict__ Qlo,
                  ushort_t* __restrict__ Khi, ushort_t* __restrict__ Klo,
                  ushort_t* __restrict__ Vthi, ushort_t* __restrict__ Vtlo,
                  int M, int N, int K)
{
    __shared__ float As[16][132];
    __shared__ float Bs[16][132];
    const int tid = threadIdx.x;
    const int tx  = tid & 15;
    const int ty  = tid >> 4;
    const int m0  = blockIdx.y * 128;
    const int n0  = blockIdx.x * 128;

    float acc[8][8];
#pragma unroll
    for (int i = 0; i < 8; ++i)
#pragma unroll
        for (int j = 0; j < 8; ++j) acc[i][j] = 0.0f;

    for (int kk = 0; kk < K; kk += 16) {
        __syncthreads();
#pragma unroll
        for (int p = 0; p < 2; ++p) {
            const int idx = tid + p * 256;
            const int m   = idx >> 2;
            const int kg  = (idx & 3) * 4;
            const float4 a = *(const float4*)&A[(size_t)(m0 + m) * K + kk + kg];
            As[kg+0][m] = a.x; As[kg+1][m] = a.y; As[kg+2][m] = a.z; As[kg+3][m] = a.w;
        }
#pragma unroll
        for (int p = 0; p < 2; ++p) {
            const int idx = tid + p * 256;
            const int kr  = idx >> 5;
            const int c   = (idx & 31) * 4;
            *(float4*)&Bs[kr][c] = *(const float4*)&B[(size_t)(kk + kr) * N + n0 + c];
        }
        __syncthreads();
#pragma unroll
        for (int k = 0; k < 16; ++k) {
            float a[8], b[8];
            *(float4*)&a[0] = *(const float4*)&As[k][ty*4];
            *(float4*)&a[4] = *(const float4*)&As[k][64 + ty*4];
            *(float4*)&b[0] = *(const float4*)&Bs[k][tx*4];
            *(float4*)&b[4] = *(const float4*)&Bs[k][64 + tx*4];
#pragma unroll
            for (int i = 0; i < 8; ++i)
#pragma unroll
                for (int j = 0; j < 8; ++j)
                    acc[i][j] = fmaf(a[i], b[j], acc[i][j]);
        }
    }

#pragma unroll
    for (int i = 0; i < 8; ++i) {
        const int m = m0 + ((i < 4) ? (ty*4 + i) : (64 + ty*4 + i - 4));
#pragma unroll
        for (int g = 0; g < 2; ++g) {
            const int n = n0 + g*64 + tx*4;
            float v[4];
#pragma unroll
            for (int j = 0; j < 4; ++j) v[j] = acc[i][g*4 + j] + bias[n + j];
            if (EPI == 0) {
                *(float4*)&O0[(size_t)m * N + n] = make_float4(v[0], v[1], v[2], v[3]);
            } else {
                const int b     = m >> 11;
                const int t     = m & 2047;
                const int which = n >> 10;          // 0=q 1=k 2=v
                const int w     = n & 1023;
                const int h     = w >> 6;
                const int d     = w & 63;
                const int bh    = b*NH + h;
                if (which < 2) {
                    const float fi = (float)(d >> 1);
                    const float tf = (float)t;
                    const float ang0 = tf * expf(fi * -0.28782313662425575f);
                    const float ang1 = tf * expf((fi + 1.0f) * -0.28782313662425575f);
                    const float s0 = sinf(ang0), c0 = cosf(ang0);
                    const float s1 = sinf(ang1), c1 = cosf(ang1);
                    const float e0 = v[0], od0 = v[1], e1 = v[2], od1 = v[3];
                    v[0] = e0*c0 - od0*s0;
                    v[1] = e0*s0 + od0*c0;
                    v[2] = e1*c1 - od1*s1;
                    v[3] = e1*s1 + od1*c1;
                    if (which == 0) {
#pragma unroll
                        for (int j = 0; j < 4; ++j) v[j] *= 0.125f;
                    }
                    ushort_t hi[4], lo[4];
#pragma unroll
                    for (int j = 0; j < 4; ++j) {
                        hi[j] = f2bf(v[j]);
                        lo[j] = f2bf(v[j] - bf2f(hi[j]));
                    }
                    ushort_t* dh = (which == 0) ? Qhi : Khi;
                    ushort_t* dl = (which == 0) ? Qlo : Klo;
                    const size_t off = ((((size_t)bh)*T_SEQ + t) << 6) + d;
                    *(short4*)&dh[off] = make_short4(hi[0], hi[1], hi[2], hi[3]);
                    *(short4*)&dl[off] = make_short4(lo[0], lo[1], lo[2], lo[3]);
                } else {
#pragma unroll
                    for (int j = 0; j < 4; ++j) {
                        const ushort_t hi = f2bf(v[j]);
                        const size_t off = (((size_t)bh)*HD + d + j)*T_SEQ + t;
                        Vthi[off] = hi;
                        Vtlo[off] = f2bf(v[j] - bf2f(hi));
                    }
                }
            }
        }
    }
}

// -------------------------------------------------------------------------
// Kernel 3: flash attention, split-bf16 MFMA, m97-style LDS staging.
// Block = 4 waves, 64 q-rows (wave w owns 16). Per kt: K/V 64-tile staged
// in LDS (hi+lo, XOR-chunk-swizzled so frag ds_read_b128 are <=2-way).
// Pipeline per kt: [issue global loads kt+1 -> regs] [S/softmax/P/PV on LDS
// tiles kt] [barrier] [ds_write kt+1] [barrier]. The vmcnt drain at the
// barrier is covered by the whole compute phase. Prefetch state = 32 VGPR.
// XCD-aware remap keeps one bh's 32 q-tiles on one XCD (L2 reuse).
// -------------------------------------------------------------------------
__global__ __launch_bounds__(256, 2)
void attn_mfma_kernel(const ushort_t* __restrict__ Qhi, const ushort_t* __restrict__ Qlo,
                      const ushort_t* __restrict__ Khi, const ushort_t* __restrict__ Klo,
                      const ushort_t* __restrict__ Vthi, const ushort_t* __restrict__ Vtlo,
                      const float* __restrict__ valid, float* __restrict__ O)
{
    __shared__ ushort_t KH[64*64];   // [row][chunk^swz] bf16 bits, 8 KB each
    __shared__ ushort_t KL[64*64];
    __shared__ ushort_t VH[64*64];   // rows = d (Vt layout)
    __shared__ ushort_t VL[64*64];
    __shared__ float Pb[4][16][68];

    const int tid  = threadIdx.x;
    const int w    = tid >> 6;
    const int ln   = tid & 63;
    const int lx   = ln & 15;
    const int quad = ln >> 4;

    const int id = blockIdx.x;
    const int qt = (id >> 3) & 31;
    const int bh = ((id >> 8) << 3) | (id & 7);
    const int b  = bh >> 4;
    const int h  = bh & 15;
    const int qrow0 = qt*64 + w*16;

    // ---- persistent Q A-fragments ----
    bf16x8 qh[2], ql[2];
    {
        const size_t qoff = (((size_t)bh)*T_SEQ + qrow0 + lx)*HD + quad*8;
        qh[0] = *(const bf16x8*)&Qhi[qoff];
        qh[1] = *(const bf16x8*)&Qhi[qoff + 32];
        ql[0] = *(const bf16x8*)&Qlo[qoff];
        ql[1] = *(const bf16x8*)&Qlo[qoff + 32];
    }

    // ---- staging geometry: wave w stages rows [w*16, w*16+16) of the tile,
    //      two 8-row groups (p=0,1); lane ln covers row w*16+p*8+(ln>>3),
    //      16-B chunk (ln&7). ----
    const int srow0 = w*16 + (ln >> 3);       // p=0 row
    const int sch   = ln & 7;
    const size_t kg0 = ((size_t)bh*T_SEQ + srow0)*HD + sch*8;       // + kt*64*HD (+p*8*HD)
    const size_t vg0 = ((size_t)bh*HD + srow0)*T_SEQ + sch*8;       // + kt*64    (+p*8*T_SEQ)
    int lw[2];
#pragma unroll
    for (int p = 0; p < 2; ++p) {
        const int r = srow0 + p*8;
        lw[p] = r*64 + ((sch ^ (r & 7)) * 8);
    }

    const float* vrow = valid + (size_t)b*T_SEQ + lx;

    f32x4 o[4];
#pragma unroll
    for (int nt = 0; nt < 4; ++nt) o[nt] = (f32x4){0.f, 0.f, 0.f, 0.f};
    float mrow[4] = {-INFINITY, -INFINITY, -INFINITY, -INFINITY};
    float lrow[4] = {0.f, 0.f, 0.f, 0.f};

    // ---- prologue: load tile kt=0, stage to LDS ----
    bf16x8 rkh[2], rkl[2], rvh[2], rvl[2];
#pragma unroll
    for (int p = 0; p < 2; ++p) {
        rkh[p] = *(const bf16x8*)&Khi [kg0 + p*8*HD];
        rkl[p] = *(const bf16x8*)&Klo [kg0 + p*8*HD];
        rvh[p] = *(const bf16x8*)&Vthi[vg0 + p*8*T_SEQ];
        rvl[p] = *(const bf16x8*)&Vtlo[vg0 + p*8*T_SEQ];
    }
#pragma unroll
    for (int p = 0; p < 2; ++p) {
        *(bf16x8*)&KH[lw[p]] = rkh[p];
        *(bf16x8*)&KL[lw[p]] = rkl[p];
        *(bf16x8*)&VH[lw[p]] = rvh[p];
        *(bf16x8*)&VL[lw[p]] = rvl[p];
    }
    __syncthreads();

    for (int kt = 0; kt < T_SEQ/64; ++kt) {
        // ---- 1. issue global prefetch for kt+1 (in flight across compute) ----
        const int ktn = (kt+1 < T_SEQ/64) ? kt+1 : kt;
#pragma unroll
        for (int p = 0; p < 2; ++p) {
            rkh[p] = *(const bf16x8*)&Khi [kg0 + (size_t)ktn*64*HD + p*8*HD];
            rkl[p] = *(const bf16x8*)&Klo [kg0 + (size_t)ktn*64*HD + p*8*HD];
            rvh[p] = *(const bf16x8*)&Vthi[vg0 + ktn*64 + p*8*T_SEQ];
            rvl[p] = *(const bf16x8*)&Vtlo[vg0 + ktn*64 + p*8*T_SEQ];
        }
        float mk[4];
#pragma unroll
        for (int nt = 0; nt < 4; ++nt) mk[nt] = vrow[kt*64 + nt*16];

        // ---- 2a. S = (Q/8) K^T from LDS (swizzled b128 reads) ----
        f32x4 s[4];
#pragma unroll
        for (int nt = 0; nt < 4; ++nt) {
            const int row = nt*16 + lx;
            const int base = row*64;
            const int sw = lx & 7;
            const int c0 = ((0*4 + quad) ^ sw) * 8;
            const int c1 = ((1*4 + quad) ^ sw) * 8;
            const bf16x8 kh0 = *(const bf16x8*)&KH[base + c0];
            const bf16x8 kh1 = *(const bf16x8*)&KH[base + c1];
            const bf16x8 kl0 = *(const bf16x8*)&KL[base + c0];
            const bf16x8 kl1 = *(const bf16x8*)&KL[base + c1];
            s[nt] = (f32x4){0.f, 0.f, 0.f, 0.f};
            s[nt] = __builtin_amdgcn_mfma_f32_16x16x32_bf16(qh[0], kh0, s[nt], 0, 0, 0);
            s[nt] = __builtin_amdgcn_mfma_f32_16x16x32_bf16(qh[1], kh1, s[nt], 0, 0, 0);
            s[nt] = __builtin_amdgcn_mfma_f32_16x16x32_bf16(ql[0], kh0, s[nt], 0, 0, 0);
            s[nt] = __builtin_amdgcn_mfma_f32_16x16x32_bf16(ql[1], kh1, s[nt], 0, 0, 0);
            s[nt] = __builtin_amdgcn_mfma_f32_16x16x32_bf16(qh[0], kl0, s[nt], 0, 0, 0);
            s[nt] = __builtin_amdgcn_mfma_f32_16x16x32_bf16(qh[1], kl1, s[nt], 0, 0, 0);
        }

        // ---- 2b. mask ----
#pragma unroll
        for (int nt = 0; nt < 4; ++nt) {
            const bool ok = mk[nt] > 0.5f;
#pragma unroll
            for (int r = 0; r < 4; ++r) s[nt][r] = ok ? s[nt][r] : -1e30f;
        }

        // ---- 2c. online softmax ----
        float alpha[4], mnew[4];
#pragma unroll
        for (int r = 0; r < 4; ++r) {
            float mt = fmaxf(fmaxf(s[0][r], s[1][r]), fmaxf(s[2][r], s[3][r]));
            mt = fmaxf(mt, __shfl_xor(mt, 1));
            mt = fmaxf(mt, __shfl_xor(mt, 2));
            mt = fmaxf(mt, __shfl_xor(mt, 4));
            mt = fmaxf(mt, __shfl_xor(mt, 8));
            mnew[r]  = fmaxf(mrow[r], mt);
            alpha[r] = __expf(mrow[r] - mnew[r]);
            mrow[r]  = mnew[r];
        }
        float p[4][4];
#pragma unroll
        for (int r = 0; r < 4; ++r) {
            float lt = 0.f;
#pragma unroll
            for (int nt = 0; nt < 4; ++nt) { p[nt][r] = __expf(s[nt][r] - mnew[r]); lt += p[nt][r]; }
            lt += __shfl_xor(lt, 1);
            lt += __shfl_xor(lt, 2);
            lt += __shfl_xor(lt, 4);
            lt += __shfl_xor(lt, 8);
            lrow[r] = lrow[r]*alpha[r] + lt;
#pragma unroll
            for (int nt = 0; nt < 4; ++nt) o[nt][r] *= alpha[r];
        }

        // ---- 2d. P: C-layout -> A-layout via wave-private slab; trunc split ----
#pragma unroll
        for (int nt = 0; nt < 4; ++nt)
#pragma unroll
            for (int r = 0; r < 4; ++r)
                Pb[w][quad*4 + r][nt*16 + lx] = p[nt][r];

        bf16x8 ph[2], pl[2];
#pragma unroll
        for (int ks = 0; ks < 2; ++ks) {
            float pv[8];
            *(f32x4*)&pv[0] = *(const f32x4*)&Pb[w][lx][ks*32 + quad*8];
            *(f32x4*)&pv[4] = *(const f32x4*)&Pb[w][lx][ks*32 + quad*8 + 4];
#pragma unroll
            for (int j = 0; j < 8; ++j) {
                const unsigned ub = fbits(pv[j]);
                ph[ks][j] = (short)(ub >> 16);
                const float lof = pv[j] - bitsf(ub & 0xffff0000u);
                pl[ks][j] = (short)(fbits(lof) >> 16);
            }
        }

        // ---- 2e. O += P V from LDS ----
#pragma unroll
        for (int nt = 0; nt < 4; ++nt) {
            const int row = nt*16 + lx;          // d-row of Vt tile
            const int base = row*64;
            const int sw = lx & 7;
            const int c0 = ((0*4 + quad) ^ sw) * 8;
            const int c1 = ((1*4 + quad) ^ sw) * 8;
            const bf16x8 vh0 = *(const bf16x8*)&VH[base + c0];
            const bf16x8 vh1 = *(const bf16x8*)&VH[base + c1];
            const bf16x8 vl0 = *(const bf16x8*)&VL[base + c0];
            const bf16x8 vl1 = *(const bf16x8*)&VL[base + c1];
            o[nt] = __builtin_amdgcn_mfma_f32_16x16x32_bf16(ph[0], vh0, o[nt], 0, 0, 0);
            o[nt] = __builtin_amdgcn_mfma_f32_16x16x32_bf16(ph[1], vh1, o[nt], 0, 0, 0);
            o[nt] = __builtin_amdgcn_mfma_f32_16x16x32_bf16(pl[0], vh0, o[nt], 0, 0, 0);
            o[nt] = __builtin_amdgcn_mfma_f32_16x16x32_bf16(pl[1], vh1, o[nt], 0, 0, 0);
            o[nt] = __builtin_amdgcn_mfma_f32_16x16x32_bf16(ph[0], vl0, o[nt], 0, 0, 0);
            o[nt] = __builtin_amdgcn_mfma_f32_16x16x32_bf16(ph[1], vl1, o[nt], 0, 0, 0);
        }

        // ---- 3/4/5. rotate tile: all reads done -> overwrite with kt+1 ----
        __syncthreads();
#pragma unroll
        for (int p2 = 0; p2 < 2; ++p2) {
            *(bf16x8*)&KH[lw[p2]] = rkh[p2];
            *(bf16x8*)&KL[lw[p2]] = rkl[p2];
            *(bf16x8*)&VH[lw[p2]] = rvh[p2];
            *(bf16x8*)&VL[lw[p2]] = rvl[p2];
        }
        __syncthreads();
    }

    // ---- normalize + store AO[b][t][h*64+dv] ----
    float inv[4];
#pragma unroll
    for (int r = 0; r < 4; ++r) inv[r] = 1.0f / lrow[r];
#pragma unroll
    for (int nt = 0; nt < 4; ++nt)
#pragma unroll
        for (int r = 0; r < 4; ++r) {
            const int t = qrow0 + quad*4 + r;
            O[(((size_t)b)*T_SEQ + t)*DM + h*HD + nt*16 + lx] = o[nt][r] * inv[r];
        }
}

// -------------------------------------------------------------------------
// Workspace layout (unchanged):
//   AO [4][2048][1024] f32 | MSK [4][2048] f32 |
//   Qhi,Qlo,Khi,Klo [64][2048][64] u16 | Vthi,Vtlo [64][64][2048] u16
// -------------------------------------------------------------------------
extern "C" void kernel_launch(void* const* d_in, const int* in_sizes, int n_in,
                              void* d_out, int out_size, void* d_ws, size_t ws_size,
                              hipStream_t stream)
{
    const float* tokens = (const float*)d_in[0];
    const int*   pad    = (const int*)d_in[1];
    const float* Wqkv   = (const float*)d_in[2];
    const float* bqkv   = (const float*)d_in[3];
    const float* Wout   = (const float*)d_in[4];
    const float* bout   = (const float*)d_in[5];
    float* out = (float*)d_out;

    const size_t SZ = (size_t)8388608;
    float* AO  = (float*)d_ws;
    float* MSK = AO + SZ;
    ushort_t* U = (ushort_t*)(MSK + 8192);
    ushort_t* Qhi  = U;
    ushort_t* Qlo  = U + SZ;
    ushort_t* Khi  = U + 2*SZ;
    ushort_t* Klo  = U + 3*SZ;
    ushort_t* Vthi = U + 4*SZ;
    ushort_t* Vtlo = U + 5*SZ;

    maskprep_kernel<<<dim3(BATCH), dim3(256), 0, stream>>>(pad, MSK);
    sgemm_kernel<1><<<dim3(24, 64), dim3(256), 0, stream>>>(
        tokens, Wqkv, bqkv, nullptr, Qhi, Qlo, Khi, Klo, Vthi, Vtlo,
        BATCH*T_SEQ, 3*DM, DM);
    attn_mfma_kernel<<<dim3(2048), dim3(256), 0, stream>>>(
        Qhi, Qlo, Khi, Klo, Vthi, Vtlo, MSK, AO);
    sgemm_kernel<0><<<dim3(8, 64), dim3(256), 0, stream>>>(
        AO, Wout, bout, out, nullptr, nullptr, nullptr, nullptr, nullptr, nullptr,
        BATCH*T_SEQ, DM, DM);
}

// Round 5
// 1193.594 us; speedup vs baseline: 1.5806x; 1.0489x over previous
//
#include <hip/hip_runtime.h>
#include <cmath>

#define T_SEQ 2048
#define NH    16
#define HD    64
#define DM    1024
#define BATCH 4

typedef __attribute__((ext_vector_type(8))) short bf16x8;
typedef __attribute__((ext_vector_type(4))) float f32x4;
typedef unsigned short ushort_t;

__device__ __forceinline__ unsigned short f2bf(float x) {   // rne fp32->bf16
    union { float f; unsigned u; } v; v.f = x;
    unsigned r = v.u + 0x7fffu + ((v.u >> 16) & 1u);
    return (unsigned short)(r >> 16);
}
__device__ __forceinline__ float bf2f(unsigned short h) {
    union { unsigned u; float f; } v; v.u = ((unsigned)h) << 16;
    return v.f;
}
__device__ __forceinline__ unsigned fbits(float x) {
    union { float f; unsigned u; } v; v.f = x; return v.u;
}
__device__ __forceinline__ float bitsf(unsigned x) {
    union { unsigned u; float f; } v; v.u = x; return v.f;
}

// -------------------------------------------------------------------------
// Kernel 1: mask prep (unchanged).
// -------------------------------------------------------------------------
__global__ void maskprep_kernel(const int* __restrict__ pad, float* __restrict__ valid)
{
    __shared__ int sall[256];
    const int b = blockIdx.x;
    const int t = threadIdx.x;
    int allp = 1;
    for (int i = t; i < T_SEQ; i += 256) allp &= (pad[b*T_SEQ + i] != 0) ? 1 : 0;
    sall[t] = allp;
    __syncthreads();
    for (int s = 128; s > 0; s >>= 1) {
        if (t < s) sall[t] &= sall[t + s];
        __syncthreads();
    }
    const int ap = sall[0];
    for (int i = t; i < T_SEQ; i += 256) {
        const int p = (pad[b*T_SEQ + i] != 0) ? 1 : 0;
        valid[b*T_SEQ + i] = (p && !ap) ? 0.0f : 1.0f;
    }
}

// -------------------------------------------------------------------------
// Kernel 2: weight transpose+split. W[K][N] fp32 -> Th/Tl[N][K] bf16 hi/lo.
// 64x64 tiles, coalesced both sides via LDS.
// -------------------------------------------------------------------------
__global__ __launch_bounds__(256)
void transpose_split_kernel(const float* __restrict__ W,
                            ushort_t* __restrict__ Th, ushort_t* __restrict__ Tl,
                            int K, int N)
{
    __shared__ float T[64][68];
    const int tid = threadIdx.x;
    const int n0 = blockIdx.x * 64;
    const int k0 = blockIdx.y * 64;
#pragma unroll
    for (int i = 0; i < 4; ++i) {
        const int kr = (tid >> 4) + i*16;
        const int nc = (tid & 15) * 4;
        const float4 v = *(const float4*)&W[(size_t)(k0 + kr)*N + n0 + nc];
        T[nc+0][kr] = v.x; T[nc+1][kr] = v.y; T[nc+2][kr] = v.z; T[nc+3][kr] = v.w;
    }
    __syncthreads();
#pragma unroll
    for (int i = 0; i < 4; ++i) {
        const int nr = (tid >> 4) + i*16;
        const int kc = (tid & 15) * 4;
        ushort_t h[4], l[4];
#pragma unroll
        for (int j = 0; j < 4; ++j) {
            const float x = T[nr][kc + j];
            h[j] = f2bf(x);
            l[j] = f2bf(x - bf2f(h[j]));
        }
        const size_t off = (size_t)(n0 + nr)*K + k0 + kc;
        *(short4*)&Th[off] = make_short4(h[0], h[1], h[2], h[3]);
        *(short4*)&Tl[off] = make_short4(l[0], l[1], l[2], l[3]);
    }
}

// -------------------------------------------------------------------------
// Kernel 3/5: split-bf16 MFMA GEMM. C[M,N] = A[M,K] @ BT[N,K]^T + bias.
// A fp32 (split to hi/lo during LDS staging, trunc-hi + rne-lo);
// B pre-split bf16 hi/lo, [n][k] layout -> contiguous 16B frags.
// 128x128 tile, BK=32, 4 waves each 64x64 quadrant (4x4 16x16 MFMA tiles,
// 3 split terms: ah*bh + ah*bl + al*bh). Pipeline: reg-prefetch kt+1 ->
// compute from LDS -> barrier -> ds_write -> barrier (proven in attn).
// EPI=0: bias + fp32 store. EPI=1: bias + RoPE (shfl pair) + Q*0.125 +
// hi/lo split + scatter to Q/K [bh][t][64], V [bh][d][t].
// -------------------------------------------------------------------------
template<int EPI>
__global__ __launch_bounds__(256, 2)
void mfma_gemm_kernel(const float* __restrict__ A,
                      const ushort_t* __restrict__ BTh, const ushort_t* __restrict__ BTl,
                      const float* __restrict__ bias,
                      float* __restrict__ O0,
                      ushort_t* __restrict__ Qhi, ushort_t* __restrict__ Qlo,
                      ushort_t* __restrict__ Khi, ushort_t* __restrict__ Klo,
                      ushort_t* __restrict__ Vthi, ushort_t* __restrict__ Vtlo,
                      int M, int N, int K)
{
    __shared__ ushort_t Ah[128][48];
    __shared__ ushort_t Al[128][48];
    __shared__ ushort_t Bh[128][48];
    __shared__ ushort_t Bl[128][48];

    const int tid  = threadIdx.x;
    const int w    = tid >> 6;
    const int ln   = tid & 63;
    const int lx   = ln & 15;
    const int quad = ln >> 4;
    const int mw   = (w >> 1) * 64;
    const int nw   = (w & 1) * 64;
    const int m0   = blockIdx.y * 128;
    const int n0   = blockIdx.x * 128;

    const int srow = tid >> 1;            // 0..127
    const int scg  = (tid & 1) * 16;      // 0|16

    f32x4 acc[4][4];
#pragma unroll
    for (int mt = 0; mt < 4; ++mt)
#pragma unroll
        for (int nt = 0; nt < 4; ++nt) acc[mt][nt] = (f32x4){0.f,0.f,0.f,0.f};

    const float*    agp = &A  [(size_t)(m0 + srow)*K + scg];
    const ushort_t* bhp = &BTh[(size_t)(n0 + srow)*K + scg];
    const ushort_t* blp = &BTl[(size_t)(n0 + srow)*K + scg];

    float  av[16];
    bf16x8 rbh[2], rbl[2];

#define LOAD_TILE(kk)  do {                                              \
        *(float4*)&av[0]  = *(const float4*)&agp[(kk)];                  \
        *(float4*)&av[4]  = *(const float4*)&agp[(kk)+4];                \
        *(float4*)&av[8]  = *(const float4*)&agp[(kk)+8];                \
        *(float4*)&av[12] = *(const float4*)&agp[(kk)+12];               \
        rbh[0] = *(const bf16x8*)&bhp[(kk)];                             \
        rbh[1] = *(const bf16x8*)&bhp[(kk)+8];                           \
        rbl[0] = *(const bf16x8*)&blp[(kk)];                             \
        rbl[1] = *(const bf16x8*)&blp[(kk)+8];                           \
    } while (0)

#define STORE_TILE() do {                                                \
        bf16x8 th, tl;                                                   \
        _Pragma("unroll")                                                \
        for (int i = 0; i < 2; ++i) {                                    \
            _Pragma("unroll")                                            \
            for (int j = 0; j < 8; ++j) {                                \
                const float x = av[i*8 + j];                             \
                const unsigned u = fbits(x);                             \
                th[j] = (short)(u >> 16);                                \
                tl[j] = (short)f2bf(x - bitsf(u & 0xffff0000u));         \
            }                                                            \
            *(bf16x8*)&Ah[srow][scg + 8*i] = th;                         \
            *(bf16x8*)&Al[srow][scg + 8*i] = tl;                         \
        }                                                                \
        *(bf16x8*)&Bh[srow][scg]     = rbh[0];                           \
        *(bf16x8*)&Bh[srow][scg + 8] = rbh[1];                           \
        *(bf16x8*)&Bl[srow][scg]     = rbl[0];                           \
        *(bf16x8*)&Bl[srow][scg + 8] = rbl[1];                           \
    } while (0)

    LOAD_TILE(0);
    STORE_TILE();
    __syncthreads();

    for (int kk = 0; kk < K; kk += 32) {
        const int kn = (kk + 32 < K) ? kk + 32 : kk;
        LOAD_TILE(kn);

        bf16x8 afh[4], afl[4], bfh[4], bfl[4];
#pragma unroll
        for (int mt = 0; mt < 4; ++mt) {
            afh[mt] = *(const bf16x8*)&Ah[mw + mt*16 + lx][quad*8];
            afl[mt] = *(const bf16x8*)&Al[mw + mt*16 + lx][quad*8];
        }
#pragma unroll
        for (int nt = 0; nt < 4; ++nt) {
            bfh[nt] = *(const bf16x8*)&Bh[nw + nt*16 + lx][quad*8];
            bfl[nt] = *(const bf16x8*)&Bl[nw + nt*16 + lx][quad*8];
        }
#pragma unroll
        for (int mt = 0; mt < 4; ++mt)
#pragma unroll
            for (int nt = 0; nt < 4; ++nt) {
                acc[mt][nt] = __builtin_amdgcn_mfma_f32_16x16x32_bf16(afh[mt], bfh[nt], acc[mt][nt], 0, 0, 0);
                acc[mt][nt] = __builtin_amdgcn_mfma_f32_16x16x32_bf16(afh[mt], bfl[nt], acc[mt][nt], 0, 0, 0);
                acc[mt][nt] = __builtin_amdgcn_mfma_f32_16x16x32_bf16(afl[mt], bfh[nt], acc[mt][nt], 0, 0, 0);
            }

        __syncthreads();
        STORE_TILE();
        __syncthreads();
    }
#undef LOAD_TILE
#undef STORE_TILE

    // ---------------- epilogue ----------------
#pragma unroll
    for (int nt = 0; nt < 4; ++nt) {
        const int n = n0 + nw + nt*16 + lx;
        if (EPI == 0) {
#pragma unroll
            for (int mt = 0; mt < 4; ++mt)
#pragma unroll
                for (int r = 0; r < 4; ++r) {
                    const int m = m0 + mw + mt*16 + quad*4 + r;
                    O0[(size_t)m*N + n] = acc[mt][nt][r] + bias[n];
                }
        } else {
            const int which = n >> 10;          // 0=q 1=k 2=v (wave-uniform)
            const int hh    = (n & 1023) >> 6;
            const int d     = n & 63;
            const float bn  = bias[n];
            const float freq = expf(-(float)(d >> 1) * 0.28782313662425575f);
            const float ssign = (lx & 1) ? 1.0f : -1.0f;
#pragma unroll
            for (int mt = 0; mt < 4; ++mt)
#pragma unroll
                for (int r = 0; r < 4; ++r) {
                    const int m  = m0 + mw + mt*16 + quad*4 + r;
                    const int b  = m >> 11;
                    const int t  = m & 2047;
                    const int bh = b*NH + hh;
                    float res = acc[mt][nt][r] + bn;
                    if (which < 2) {
                        const float ang = (float)t * freq;
                        const float sn = sinf(ang), cs = cosf(ang);
                        const float prt = __shfl_xor(res, 1);
                        res = res*cs + ssign*prt*sn;
                        if (which == 0) res *= 0.125f;
                        const ushort_t hi = f2bf(res);
                        const ushort_t lo = f2bf(res - bf2f(hi));
                        const size_t off = ((((size_t)bh)*T_SEQ + t) << 6) + d;
                        if (which == 0) { Qhi[off] = hi; Qlo[off] = lo; }
                        else            { Khi[off] = hi; Klo[off] = lo; }
                    } else {
                        const ushort_t hi = f2bf(res);
                        const ushort_t lo = f2bf(res - bf2f(hi));
                        const size_t off = (((size_t)bh)*HD + d)*T_SEQ + t;
                        Vthi[off] = hi; Vtlo[off] = lo;
                    }
                }
        }
    }
}

// -------------------------------------------------------------------------
// Kernel 4: flash attention (unchanged from round 4 — verified working).
// -------------------------------------------------------------------------
__global__ __launch_bounds__(256, 2)
void attn_mfma_kernel(const ushort_t* __restrict__ Qhi, const ushort_t* __restrict__ Qlo,
                      const ushort_t* __restrict__ Khi, const ushort_t* __restrict__ Klo,
                      const ushort_t* __restrict__ Vthi, const ushort_t* __restrict__ Vtlo,
                      const float* __restrict__ valid, float* __restrict__ O)
{
    __shared__ ushort_t KH[64*64];
    __shared__ ushort_t KL[64*64];
    __shared__ ushort_t VH[64*64];
    __shared__ ushort_t VL[64*64];
    __shared__ float Pb[4][16][68];

    const int tid  = threadIdx.x;
    const int w    = tid >> 6;
    const int ln   = tid & 63;
    const int lx   = ln & 15;
    const int quad = ln >> 4;

    const int id = blockIdx.x;
    const int qt = (id >> 3) & 31;
    const int bh = ((id >> 8) << 3) | (id & 7);
    const int b  = bh >> 4;
    const int h  = bh & 15;
    const int qrow0 = qt*64 + w*16;

    bf16x8 qh[2], ql[2];
    {
        const size_t qoff = (((size_t)bh)*T_SEQ + qrow0 + lx)*HD + quad*8;
        qh[0] = *(const bf16x8*)&Qhi[qoff];
        qh[1] = *(const bf16x8*)&Qhi[qoff + 32];
        ql[0] = *(const bf16x8*)&Qlo[qoff];
        ql[1] = *(const bf16x8*)&Qlo[qoff + 32];
    }

    const int srow0 = w*16 + (ln >> 3);
    const int sch   = ln & 7;
    const size_t kg0 = ((size_t)bh*T_SEQ + srow0)*HD + sch*8;
    const size_t vg0 = ((size_t)bh*HD + srow0)*T_SEQ + sch*8;
    int lw[2];
#pragma unroll
    for (int p = 0; p < 2; ++p) {
        const int r = srow0 + p*8;
        lw[p] = r*64 + ((sch ^ (r & 7)) * 8);
    }

    const float* vrow = valid + (size_t)b*T_SEQ + lx;

    f32x4 o[4];
#pragma unroll
    for (int nt = 0; nt < 4; ++nt) o[nt] = (f32x4){0.f, 0.f, 0.f, 0.f};
    float mrow[4] = {-INFINITY, -INFINITY, -INFINITY, -INFINITY};
    float lrow[4] = {0.f, 0.f, 0.f, 0.f};

    bf16x8 rkh[2], rkl[2], rvh[2], rvl[2];
#pragma unroll
    for (int p = 0; p < 2; ++p) {
        rkh[p] = *(const bf16x8*)&Khi [kg0 + p*8*HD];
        rkl[p] = *(const bf16x8*)&Klo [kg0 + p*8*HD];
        rvh[p] = *(const bf16x8*)&Vthi[vg0 + p*8*T_SEQ];
        rvl[p] = *(const bf16x8*)&Vtlo[vg0 + p*8*T_SEQ];
    }
#pragma unroll
    for (int p = 0; p < 2; ++p) {
        *(bf16x8*)&KH[lw[p]] = rkh[p];
        *(bf16x8*)&KL[lw[p]] = rkl[p];
        *(bf16x8*)&VH[lw[p]] = rvh[p];
        *(bf16x8*)&VL[lw[p]] = rvl[p];
    }
    __syncthreads();

    for (int kt = 0; kt < T_SEQ/64; ++kt) {
        const int ktn = (kt+1 < T_SEQ/64) ? kt+1 : kt;
#pragma unroll
        for (int p = 0; p < 2; ++p) {
            rkh[p] = *(const bf16x8*)&Khi [kg0 + (size_t)ktn*64*HD + p*8*HD];
            rkl[p] = *(const bf16x8*)&Klo [kg0 + (size_t)ktn*64*HD + p*8*HD];
            rvh[p] = *(const bf16x8*)&Vthi[vg0 + ktn*64 + p*8*T_SEQ];
            rvl[p] = *(const bf16x8*)&Vtlo[vg0 + ktn*64 + p*8*T_SEQ];
        }
        float mk[4];
#pragma unroll
        for (int nt = 0; nt < 4; ++nt) mk[nt] = vrow[kt*64 + nt*16];

        f32x4 s[4];
#pragma unroll
        for (int nt = 0; nt < 4; ++nt) {
            const int row = nt*16 + lx;
            const int base = row*64;
            const int sw = lx & 7;
            const int c0 = ((0*4 + quad) ^ sw) * 8;
            const int c1 = ((1*4 + quad) ^ sw) * 8;
            const bf16x8 kh0 = *(const bf16x8*)&KH[base + c0];
            const bf16x8 kh1 = *(const bf16x8*)&KH[base + c1];
            const bf16x8 kl0 = *(const bf16x8*)&KL[base + c0];
            const bf16x8 kl1 = *(const bf16x8*)&KL[base + c1];
            s[nt] = (f32x4){0.f, 0.f, 0.f, 0.f};
            s[nt] = __builtin_amdgcn_mfma_f32_16x16x32_bf16(qh[0], kh0, s[nt], 0, 0, 0);
            s[nt] = __builtin_amdgcn_mfma_f32_16x16x32_bf16(qh[1], kh1, s[nt], 0, 0, 0);
            s[nt] = __builtin_amdgcn_mfma_f32_16x16x32_bf16(ql[0], kh0, s[nt], 0, 0, 0);
            s[nt] = __builtin_amdgcn_mfma_f32_16x16x32_bf16(ql[1], kh1, s[nt], 0, 0, 0);
            s[nt] = __builtin_amdgcn_mfma_f32_16x16x32_bf16(qh[0], kl0, s[nt], 0, 0, 0);
            s[nt] = __builtin_amdgcn_mfma_f32_16x16x32_bf16(qh[1], kl1, s[nt], 0, 0, 0);
        }

#pragma unroll
        for (int nt = 0; nt < 4; ++nt) {
            const bool ok = mk[nt] > 0.5f;
#pragma unroll
            for (int r = 0; r < 4; ++r) s[nt][r] = ok ? s[nt][r] : -1e30f;
        }

        float alpha[4], mnew[4];
#pragma unroll
        for (int r = 0; r < 4; ++r) {
            float mt = fmaxf(fmaxf(s[0][r], s[1][r]), fmaxf(s[2][r], s[3][r]));
            mt = fmaxf(mt, __shfl_xor(mt, 1));
            mt = fmaxf(mt, __shfl_xor(mt, 2));
            mt = fmaxf(mt, __shfl_xor(mt, 4));
            mt = fmaxf(mt, __shfl_xor(mt, 8));
            mnew[r]  = fmaxf(mrow[r], mt);
            alpha[r] = __expf(mrow[r] - mnew[r]);
            mrow[r]  = mnew[r];
        }
        float p[4][4];
#pragma unroll
        for (int r = 0; r < 4; ++r) {
            float lt = 0.f;
#pragma unroll
            for (int nt = 0; nt < 4; ++nt) { p[nt][r] = __expf(s[nt][r] - mnew[r]); lt += p[nt][r]; }
            lt += __shfl_xor(lt, 1);
            lt += __shfl_xor(lt, 2);
            lt += __shfl_xor(lt, 4);
            lt += __shfl_xor(lt, 8);
            lrow[r] = lrow[r]*alpha[r] + lt;
#pragma unroll
            for (int nt = 0; nt < 4; ++nt) o[nt][r] *= alpha[r];
        }

#pragma unroll
        for (int nt = 0; nt < 4; ++nt)
#pragma unroll
            for (int r = 0; r < 4; ++r)
                Pb[w][quad*4 + r][nt*16 + lx] = p[nt][r];

        bf16x8 ph[2], pl[2];
#pragma unroll
        for (int ks = 0; ks < 2; ++ks) {
            float pv[8];
            *(f32x4*)&pv[0] = *(const f32x4*)&Pb[w][lx][ks*32 + quad*8];
            *(f32x4*)&pv[4] = *(const f32x4*)&Pb[w][lx][ks*32 + quad*8 + 4];
#pragma unroll
            for (int j = 0; j < 8; ++j) {
                const unsigned ub = fbits(pv[j]);
                ph[ks][j] = (short)(ub >> 16);
                const float lof = pv[j] - bitsf(ub & 0xffff0000u);
                pl[ks][j] = (short)(fbits(lof) >> 16);
            }
        }

#pragma unroll
        for (int nt = 0; nt < 4; ++nt) {
            const int row = nt*16 + lx;
            const int base = row*64;
            const int sw = lx & 7;
            const int c0 = ((0*4 + quad) ^ sw) * 8;
            const int c1 = ((1*4 + quad) ^ sw) * 8;
            const bf16x8 vh0 = *(const bf16x8*)&VH[base + c0];
            const bf16x8 vh1 = *(const bf16x8*)&VH[base + c1];
            const bf16x8 vl0 = *(const bf16x8*)&VL[base + c0];
            const bf16x8 vl1 = *(const bf16x8*)&VL[base + c1];
            o[nt] = __builtin_amdgcn_mfma_f32_16x16x32_bf16(ph[0], vh0, o[nt], 0, 0, 0);
            o[nt] = __builtin_amdgcn_mfma_f32_16x16x32_bf16(ph[1], vh1, o[nt], 0, 0, 0);
            o[nt] = __builtin_amdgcn_mfma_f32_16x16x32_bf16(pl[0], vh0, o[nt], 0, 0, 0);
            o[nt] = __builtin_amdgcn_mfma_f32_16x16x32_bf16(pl[1], vh1, o[nt], 0, 0, 0);
            o[nt] = __builtin_amdgcn_mfma_f32_16x16x32_bf16(ph[0], vl0, o[nt], 0, 0, 0);
            o[nt] = __builtin_amdgcn_mfma_f32_16x16x32_bf16(ph[1], vl1, o[nt], 0, 0, 0);
        }

        __syncthreads();
#pragma unroll
        for (int p2 = 0; p2 < 2; ++p2) {
            *(bf16x8*)&KH[lw[p2]] = rkh[p2];
            *(bf16x8*)&KL[lw[p2]] = rkl[p2];
            *(bf16x8*)&VH[lw[p2]] = rvh[p2];
            *(bf16x8*)&VL[lw[p2]] = rvl[p2];
        }
        __syncthreads();
    }

    float inv[4];
#pragma unroll
    for (int r = 0; r < 4; ++r) inv[r] = 1.0f / lrow[r];
#pragma unroll
    for (int nt = 0; nt < 4; ++nt)
#pragma unroll
        for (int r = 0; r < 4; ++r) {
            const int t = qrow0 + quad*4 + r;
            O[(((size_t)b)*T_SEQ + t)*DM + h*HD + nt*16 + lx] = o[nt][r] * inv[r];
        }
}

// -------------------------------------------------------------------------
// Workspace (128.03 MiB, proven size, alias plan):
//   [0]           Qhi,Qlo,Khi,Klo,Vthi,Vtlo : 6 x 16 MiB  (u16)
//   [6*SZ]        MSK : 8192 f32 (32 KiB)
//   [6*SZ+16KiB]  union{ WqkvT hi/lo (12 MiB, dies at QKV-GEMM end)
//                        AO fp32 (32 MiB, born at attention) }
//   WoutT hi/lo (4 MiB) reuses the dead Qhi region after attention.
// -------------------------------------------------------------------------
extern "C" void kernel_launch(void* const* d_in, const int* in_sizes, int n_in,
                              void* d_out, int out_size, void* d_ws, size_t ws_size,
                              hipStream_t stream)
{
    const float* tokens = (const float*)d_in[0];
    const int*   pad    = (const int*)d_in[1];
    const float* Wqkv   = (const float*)d_in[2];
    const float* bqkv   = (const float*)d_in[3];
    const float* Wout   = (const float*)d_in[4];
    const float* bout   = (const float*)d_in[5];
    float* out = (float*)d_out;

    const size_t SZ = (size_t)8388608;
    ushort_t* U = (ushort_t*)d_ws;
    ushort_t* Qhi  = U;
    ushort_t* Qlo  = U + SZ;
    ushort_t* Khi  = U + 2*SZ;
    ushort_t* Klo  = U + 3*SZ;
    ushort_t* Vthi = U + 4*SZ;
    ushort_t* Vtlo = U + 5*SZ;
    float* MSK = (float*)(U + 6*SZ);
    float* AO  = MSK + 8192;                      // 32 MiB region
    ushort_t* WqkvTh = (ushort_t*)AO;             // aliased (disjoint lifetime)
    ushort_t* WqkvTl = WqkvTh + (size_t)3*DM*DM;  // 3.15M elems
    ushort_t* WoutTh = Qhi;                       // reused after attention
    ushort_t* WoutTl = Qhi + (size_t)DM*DM;

    maskprep_kernel<<<dim3(BATCH), dim3(256), 0, stream>>>(pad, MSK);
    transpose_split_kernel<<<dim3(48, 16), dim3(256), 0, stream>>>(
        Wqkv, WqkvTh, WqkvTl, DM, 3*DM);
    mfma_gemm_kernel<1><<<dim3(24, 64), dim3(256), 0, stream>>>(
        tokens, WqkvTh, WqkvTl, bqkv, nullptr,
        Qhi, Qlo, Khi, Klo, Vthi, Vtlo, BATCH*T_SEQ, 3*DM, DM);
    attn_mfma_kernel<<<dim3(2048), dim3(256), 0, stream>>>(
        Qhi, Qlo, Khi, Klo, Vthi, Vtlo, MSK, AO);
    transpose_split_kernel<<<dim3(16, 16), dim3(256), 0, stream>>>(
        Wout, WoutTh, WoutTl, DM, DM);
    mfma_gemm_kernel<0><<<dim3(8, 64), dim3(256), 0, stream>>>(
        AO, WoutTh, WoutTl, bout, out,
        nullptr, nullptr, nullptr, nullptr, nullptr, nullptr, BATCH*T_SEQ, DM, DM);
}

// Round 6
// 1149.202 us; speedup vs baseline: 1.6416x; 1.0386x over previous
//
#include <hip/hip_runtime.h>
#include <cmath>

#define T_SEQ 2048
#define NH    16
#define HD    64
#define DM    1024
#define BATCH 4

typedef __attribute__((ext_vector_type(8))) short bf16x8;
typedef __attribute__((ext_vector_type(4))) float f32x4;
typedef unsigned short ushort_t;

__device__ __forceinline__ unsigned short f2bf(float x) {   // rne fp32->bf16
    union { float f; unsigned u; } v; v.f = x;
    unsigned r = v.u + 0x7fffu + ((v.u >> 16) & 1u);
    return (unsigned short)(r >> 16);
}
__device__ __forceinline__ float bf2f(unsigned short h) {
    union { unsigned u; float f; } v; v.u = ((unsigned)h) << 16;
    return v.f;
}
__device__ __forceinline__ unsigned fbits(float x) {
    union { float f; unsigned u; } v; v.f = x; return v.u;
}
__device__ __forceinline__ float bitsf(unsigned x) {
    union { unsigned u; float f; } v; v.u = x; return v.f;
}

// -------------------------------------------------------------------------
// Kernel 1: mask prep (unchanged).
// -------------------------------------------------------------------------
__global__ void maskprep_kernel(const int* __restrict__ pad, float* __restrict__ valid)
{
    __shared__ int sall[256];
    const int b = blockIdx.x;
    const int t = threadIdx.x;
    int allp = 1;
    for (int i = t; i < T_SEQ; i += 256) allp &= (pad[b*T_SEQ + i] != 0) ? 1 : 0;
    sall[t] = allp;
    __syncthreads();
    for (int s = 128; s > 0; s >>= 1) {
        if (t < s) sall[t] &= sall[t + s];
        __syncthreads();
    }
    const int ap = sall[0];
    for (int i = t; i < T_SEQ; i += 256) {
        const int p = (pad[b*T_SEQ + i] != 0) ? 1 : 0;
        valid[b*T_SEQ + i] = (p && !ap) ? 0.0f : 1.0f;
    }
}

// -------------------------------------------------------------------------
// Kernel 2: weight transpose+split (unchanged).
// -------------------------------------------------------------------------
__global__ __launch_bounds__(256)
void transpose_split_kernel(const float* __restrict__ W,
                            ushort_t* __restrict__ Th, ushort_t* __restrict__ Tl,
                            int K, int N)
{
    __shared__ float T[64][68];
    const int tid = threadIdx.x;
    const int n0 = blockIdx.x * 64;
    const int k0 = blockIdx.y * 64;
#pragma unroll
    for (int i = 0; i < 4; ++i) {
        const int kr = (tid >> 4) + i*16;
        const int nc = (tid & 15) * 4;
        const float4 v = *(const float4*)&W[(size_t)(k0 + kr)*N + n0 + nc];
        T[nc+0][kr] = v.x; T[nc+1][kr] = v.y; T[nc+2][kr] = v.z; T[nc+3][kr] = v.w;
    }
    __syncthreads();
#pragma unroll
    for (int i = 0; i < 4; ++i) {
        const int nr = (tid >> 4) + i*16;
        const int kc = (tid & 15) * 4;
        ushort_t h[4], l[4];
#pragma unroll
        for (int j = 0; j < 4; ++j) {
            const float x = T[nr][kc + j];
            h[j] = f2bf(x);
            l[j] = f2bf(x - bf2f(h[j]));
        }
        const size_t off = (size_t)(n0 + nr)*K + k0 + kc;
        *(short4*)&Th[off] = make_short4(h[0], h[1], h[2], h[3]);
        *(short4*)&Tl[off] = make_short4(l[0], l[1], l[2], l[3]);
    }
}

// -------------------------------------------------------------------------
// Kernel 3/5: split-bf16 MFMA GEMM, 128x128xBK32 (unchanged k-loop).
// EPI=1 epilogue REWORKED: two m-half phases through the (dead) staging LDS,
// Q/K staged [m][n], V staged transposed [n][m]; readout = 16B/lane
// coalesced stores of bf16 hi/lo. Kills the 34x HBM write amplification the
// old scalar 2B scatter stores caused (R5: WRITE_SIZE 3.25 GB vs 96 MB).
// -------------------------------------------------------------------------
template<int EPI>
__global__ __launch_bounds__(256, 2)
void mfma_gemm_kernel(const float* __restrict__ A,
                      const ushort_t* __restrict__ BTh, const ushort_t* __restrict__ BTl,
                      const float* __restrict__ bias,
                      float* __restrict__ O0,
                      ushort_t* __restrict__ Qhi, ushort_t* __restrict__ Qlo,
                      ushort_t* __restrict__ Khi, ushort_t* __restrict__ Klo,
                      ushort_t* __restrict__ Vthi, ushort_t* __restrict__ Vtlo,
                      int M, int N, int K)
{
    __shared__ __align__(16) char smem[49152];
    ushort_t* Ah = (ushort_t*)smem;        // [128][48] each
    ushort_t* Al = Ah + 128*48;
    ushort_t* Bh = Al + 128*48;
    ushort_t* Bl = Bh + 128*48;

    const int tid  = threadIdx.x;
    const int w    = tid >> 6;
    const int ln   = tid & 63;
    const int lx   = ln & 15;
    const int quad = ln >> 4;
    const int mw   = (w >> 1) * 64;
    const int nw   = (w & 1) * 64;
    const int m0   = blockIdx.y * 128;
    const int n0   = blockIdx.x * 128;

    const int srow = tid >> 1;            // 0..127
    const int scg  = (tid & 1) * 16;      // 0|16

    f32x4 acc[4][4];
#pragma unroll
    for (int mt = 0; mt < 4; ++mt)
#pragma unroll
        for (int nt = 0; nt < 4; ++nt) acc[mt][nt] = (f32x4){0.f,0.f,0.f,0.f};

    const float*    agp = &A  [(size_t)(m0 + srow)*K + scg];
    const ushort_t* bhp = &BTh[(size_t)(n0 + srow)*K + scg];
    const ushort_t* blp = &BTl[(size_t)(n0 + srow)*K + scg];

    float  av[16];
    bf16x8 rbh[2], rbl[2];

#define LOAD_TILE(kk)  do {                                              \
        *(float4*)&av[0]  = *(const float4*)&agp[(kk)];                  \
        *(float4*)&av[4]  = *(const float4*)&agp[(kk)+4];                \
        *(float4*)&av[8]  = *(const float4*)&agp[(kk)+8];                \
        *(float4*)&av[12] = *(const float4*)&agp[(kk)+12];               \
        rbh[0] = *(const bf16x8*)&bhp[(kk)];                             \
        rbh[1] = *(const bf16x8*)&bhp[(kk)+8];                           \
        rbl[0] = *(const bf16x8*)&blp[(kk)];                             \
        rbl[1] = *(const bf16x8*)&blp[(kk)+8];                           \
    } while (0)

#define STORE_TILE() do {                                                \
        bf16x8 th, tl;                                                   \
        _Pragma("unroll")                                                \
        for (int i = 0; i < 2; ++i) {                                    \
            _Pragma("unroll")                                            \
            for (int j = 0; j < 8; ++j) {                                \
                const float x = av[i*8 + j];                             \
                const unsigned u = fbits(x);                             \
                th[j] = (short)(u >> 16);                                \
                tl[j] = (short)f2bf(x - bitsf(u & 0xffff0000u));         \
            }                                                            \
            *(bf16x8*)&Ah[srow*48 + scg + 8*i] = th;                     \
            *(bf16x8*)&Al[srow*48 + scg + 8*i] = tl;                     \
        }                                                                \
        *(bf16x8*)&Bh[srow*48 + scg]     = rbh[0];                       \
        *(bf16x8*)&Bh[srow*48 + scg + 8] = rbh[1];                       \
        *(bf16x8*)&Bl[srow*48 + scg]     = rbl[0];                       \
        *(bf16x8*)&Bl[srow*48 + scg + 8] = rbl[1];                       \
    } while (0)

    LOAD_TILE(0);
    STORE_TILE();
    __syncthreads();

    for (int kk = 0; kk < K; kk += 32) {
        const int kn = (kk + 32 < K) ? kk + 32 : kk;
        LOAD_TILE(kn);

        bf16x8 afh[4], afl[4], bfh[4], bfl[4];
#pragma unroll
        for (int mt = 0; mt < 4; ++mt) {
            afh[mt] = *(const bf16x8*)&Ah[(mw + mt*16 + lx)*48 + quad*8];
            afl[mt] = *(const bf16x8*)&Al[(mw + mt*16 + lx)*48 + quad*8];
        }
#pragma unroll
        for (int nt = 0; nt < 4; ++nt) {
            bfh[nt] = *(const bf16x8*)&Bh[(nw + nt*16 + lx)*48 + quad*8];
            bfl[nt] = *(const bf16x8*)&Bl[(nw + nt*16 + lx)*48 + quad*8];
        }
#pragma unroll
        for (int mt = 0; mt < 4; ++mt)
#pragma unroll
            for (int nt = 0; nt < 4; ++nt) {
                acc[mt][nt] = __builtin_amdgcn_mfma_f32_16x16x32_bf16(afh[mt], bfh[nt], acc[mt][nt], 0, 0, 0);
                acc[mt][nt] = __builtin_amdgcn_mfma_f32_16x16x32_bf16(afh[mt], bfl[nt], acc[mt][nt], 0, 0, 0);
                acc[mt][nt] = __builtin_amdgcn_mfma_f32_16x16x32_bf16(afl[mt], bfh[nt], acc[mt][nt], 0, 0, 0);
            }

        __syncthreads();
        STORE_TILE();
        __syncthreads();
    }
#undef LOAD_TILE
#undef STORE_TILE

    // ---------------- epilogue ----------------
    if (EPI == 0) {
#pragma unroll
        for (int nt = 0; nt < 4; ++nt) {
            const int n = n0 + nw + nt*16 + lx;
#pragma unroll
            for (int mt = 0; mt < 4; ++mt)
#pragma unroll
                for (int r = 0; r < 4; ++r) {
                    const int m = m0 + mw + mt*16 + quad*4 + r;
                    O0[(size_t)m*N + n] = acc[mt][nt][r] + bias[n];
                }
        }
    } else {
        const int which = n0 >> 10;           // block-uniform: 0=q 1=k 2=v
        const int hbase = (n0 & 1023) >> 6;
        const int b     = m0 >> 11;
        const int t0    = m0 & 2047;
        float* Ct = (float*)smem;             // Q/K: [64][132]; V: [128][68]
        const float ssign = (lx & 1) ? 1.0f : -1.0f;

        for (int mhalf = 0; mhalf < 2; ++mhalf) {
            __syncthreads();                  // LDS reuse / phase separation
            if (mw == mhalf*64) {             // owning waves stage their C
                if (which < 2) {
#pragma unroll
                    for (int nt = 0; nt < 4; ++nt) {
                        const int nl = nw + nt*16 + lx;
                        const int d  = nl & 63;
                        const float bn = bias[n0 + nl];
                        const float freq = expf(-(float)(d >> 1) * 0.28782313662425575f);
#pragma unroll
                        for (int mt = 0; mt < 4; ++mt)
#pragma unroll
                            for (int r = 0; r < 4; ++r) {
                                const int ml = mt*16 + quad*4 + r;
                                const int t  = t0 + mhalf*64 + ml;
                                float res = acc[mt][nt][r] + bn;
                                const float ang = (float)t * freq;
                                const float sn = sinf(ang), cs = cosf(ang);
                                const float prt = __shfl_xor(res, 1);
                                res = res*cs + ssign*prt*sn;
                                if (which == 0) res *= 0.125f;
                                Ct[ml*132 + nl] = res;
                            }
                    }
                } else {
#pragma unroll
                    for (int nt = 0; nt < 4; ++nt) {
                        const int nl = nw + nt*16 + lx;
                        const float bn = bias[n0 + nl];
#pragma unroll
                        for (int mt = 0; mt < 4; ++mt)
#pragma unroll
                            for (int r = 0; r < 4; ++r) {
                                const int ml = mt*16 + quad*4 + r;
                                Ct[nl*68 + ml] = acc[mt][nt][r] + bn;
                            }
                    }
                }
            }
            __syncthreads();
            // coalesced readout: all 4 waves, 16B/lane stores
            if (which < 2) {
                ushort_t* dH = which ? Khi : Qhi;
                ushort_t* dL = which ? Klo : Qlo;
#pragma unroll
                for (int ui = 0; ui < 4; ++ui) {
                    const int u  = w*4 + ui;
                    const int hl = u >> 3, titer = u & 7;
                    const int tl = titer*8 + (ln >> 3);
                    const int dg = (ln & 7) * 8;
                    const float* src = &Ct[tl*132 + hl*64 + dg];
                    float v[8];
                    *(f32x4*)&v[0] = *(const f32x4*)src;
                    *(f32x4*)&v[4] = *(const f32x4*)(src + 4);
                    bf16x8 h8, l8;
#pragma unroll
                    for (int j = 0; j < 8; ++j) {
                        const unsigned u32 = fbits(v[j]);
                        h8[j] = (short)(u32 >> 16);
                        l8[j] = (short)f2bf(v[j] - bitsf(u32 & 0xffff0000u));
                    }
                    const int t  = t0 + mhalf*64 + tl;
                    const int bh = b*NH + hbase + hl;
                    const size_t off = (((size_t)bh)*T_SEQ + t)*64 + dg;
                    *(bf16x8*)&dH[off] = h8;
                    *(bf16x8*)&dL[off] = l8;
                }
            } else {
#pragma unroll
                for (int ui = 0; ui < 4; ++ui) {
                    const int u  = w*4 + ui;
                    const int nr = u*8 + (ln >> 3);
                    const int d  = nr & 63, hl = nr >> 6;
                    const int tg = (ln & 7) * 8;
                    const float* src = &Ct[nr*68 + tg];
                    float v[8];
                    *(f32x4*)&v[0] = *(const f32x4*)src;
                    *(f32x4*)&v[4] = *(const f32x4*)(src + 4);
                    bf16x8 h8, l8;
#pragma unroll
                    for (int j = 0; j < 8; ++j) {
                        const unsigned u32 = fbits(v[j]);
                        h8[j] = (short)(u32 >> 16);
                        l8[j] = (short)f2bf(v[j] - bitsf(u32 & 0xffff0000u));
                    }
                    const int bh = b*NH + hbase + hl;
                    const size_t off = (((size_t)bh)*HD + d)*T_SEQ + t0 + mhalf*64 + tg;
                    *(bf16x8*)&Vthi[off] = h8;
                    *(bf16x8*)&Vtlo[off] = l8;
                }
            }
        }
    }
}

// -------------------------------------------------------------------------
// Kernel 4: flash attention (unchanged from round 4 — verified working).
// -------------------------------------------------------------------------
__global__ __launch_bounds__(256, 2)
void attn_mfma_kernel(const ushort_t* __restrict__ Qhi, const ushort_t* __restrict__ Qlo,
                      const ushort_t* __restrict__ Khi, const ushort_t* __restrict__ Klo,
                      const ushort_t* __restrict__ Vthi, const ushort_t* __restrict__ Vtlo,
                      const float* __restrict__ valid, float* __restrict__ O)
{
    __shared__ ushort_t KH[64*64];
    __shared__ ushort_t KL[64*64];
    __shared__ ushort_t VH[64*64];
    __shared__ ushort_t VL[64*64];
    __shared__ float Pb[4][16][68];

    const int tid  = threadIdx.x;
    const int w    = tid >> 6;
    const int ln   = tid & 63;
    const int lx   = ln & 15;
    const int quad = ln >> 4;

    const int id = blockIdx.x;
    const int qt = (id >> 3) & 31;
    const int bh = ((id >> 8) << 3) | (id & 7);
    const int b  = bh >> 4;
    const int h  = bh & 15;
    const int qrow0 = qt*64 + w*16;

    bf16x8 qh[2], ql[2];
    {
        const size_t qoff = (((size_t)bh)*T_SEQ + qrow0 + lx)*HD + quad*8;
        qh[0] = *(const bf16x8*)&Qhi[qoff];
        qh[1] = *(const bf16x8*)&Qhi[qoff + 32];
        ql[0] = *(const bf16x8*)&Qlo[qoff];
        ql[1] = *(const bf16x8*)&Qlo[qoff + 32];
    }

    const int srow0 = w*16 + (ln >> 3);
    const int sch   = ln & 7;
    const size_t kg0 = ((size_t)bh*T_SEQ + srow0)*HD + sch*8;
    const size_t vg0 = ((size_t)bh*HD + srow0)*T_SEQ + sch*8;
    int lw[2];
#pragma unroll
    for (int p = 0; p < 2; ++p) {
        const int r = srow0 + p*8;
        lw[p] = r*64 + ((sch ^ (r & 7)) * 8);
    }

    const float* vrow = valid + (size_t)b*T_SEQ + lx;

    f32x4 o[4];
#pragma unroll
    for (int nt = 0; nt < 4; ++nt) o[nt] = (f32x4){0.f, 0.f, 0.f, 0.f};
    float mrow[4] = {-INFINITY, -INFINITY, -INFINITY, -INFINITY};
    float lrow[4] = {0.f, 0.f, 0.f, 0.f};

    bf16x8 rkh[2], rkl[2], rvh[2], rvl[2];
#pragma unroll
    for (int p = 0; p < 2; ++p) {
        rkh[p] = *(const bf16x8*)&Khi [kg0 + p*8*HD];
        rkl[p] = *(const bf16x8*)&Klo [kg0 + p*8*HD];
        rvh[p] = *(const bf16x8*)&Vthi[vg0 + p*8*T_SEQ];
        rvl[p] = *(const bf16x8*)&Vtlo[vg0 + p*8*T_SEQ];
    }
#pragma unroll
    for (int p = 0; p < 2; ++p) {
        *(bf16x8*)&KH[lw[p]] = rkh[p];
        *(bf16x8*)&KL[lw[p]] = rkl[p];
        *(bf16x8*)&VH[lw[p]] = rvh[p];
        *(bf16x8*)&VL[lw[p]] = rvl[p];
    }
    __syncthreads();

    for (int kt = 0; kt < T_SEQ/64; ++kt) {
        const int ktn = (kt+1 < T_SEQ/64) ? kt+1 : kt;
#pragma unroll
        for (int p = 0; p < 2; ++p) {
            rkh[p] = *(const bf16x8*)&Khi [kg0 + (size_t)ktn*64*HD + p*8*HD];
            rkl[p] = *(const bf16x8*)&Klo [kg0 + (size_t)ktn*64*HD + p*8*HD];
            rvh[p] = *(const bf16x8*)&Vthi[vg0 + ktn*64 + p*8*T_SEQ];
            rvl[p] = *(const bf16x8*)&Vtlo[vg0 + ktn*64 + p*8*T_SEQ];
        }
        float mk[4];
#pragma unroll
        for (int nt = 0; nt < 4; ++nt) mk[nt] = vrow[kt*64 + nt*16];

        f32x4 s[4];
#pragma unroll
        for (int nt = 0; nt < 4; ++nt) {
            const int row = nt*16 + lx;
            const int base = row*64;
            const int sw = lx & 7;
            const int c0 = ((0*4 + quad) ^ sw) * 8;
            const int c1 = ((1*4 + quad) ^ sw) * 8;
            const bf16x8 kh0 = *(const bf16x8*)&KH[base + c0];
            const bf16x8 kh1 = *(const bf16x8*)&KH[base + c1];
            const bf16x8 kl0 = *(const bf16x8*)&KL[base + c0];
            const bf16x8 kl1 = *(const bf16x8*)&KL[base + c1];
            s[nt] = (f32x4){0.f, 0.f, 0.f, 0.f};
            s[nt] = __builtin_amdgcn_mfma_f32_16x16x32_bf16(qh[0], kh0, s[nt], 0, 0, 0);
            s[nt] = __builtin_amdgcn_mfma_f32_16x16x32_bf16(qh[1], kh1, s[nt], 0, 0, 0);
            s[nt] = __builtin_amdgcn_mfma_f32_16x16x32_bf16(ql[0], kh0, s[nt], 0, 0, 0);
            s[nt] = __builtin_amdgcn_mfma_f32_16x16x32_bf16(ql[1], kh1, s[nt], 0, 0, 0);
            s[nt] = __builtin_amdgcn_mfma_f32_16x16x32_bf16(qh[0], kl0, s[nt], 0, 0, 0);
            s[nt] = __builtin_amdgcn_mfma_f32_16x16x32_bf16(qh[1], kl1, s[nt], 0, 0, 0);
        }

#pragma unroll
        for (int nt = 0; nt < 4; ++nt) {
            const bool ok = mk[nt] > 0.5f;
#pragma unroll
            for (int r = 0; r < 4; ++r) s[nt][r] = ok ? s[nt][r] : -1e30f;
        }

        float alpha[4], mnew[4];
#pragma unroll
        for (int r = 0; r < 4; ++r) {
            float mt = fmaxf(fmaxf(s[0][r], s[1][r]), fmaxf(s[2][r], s[3][r]));
            mt = fmaxf(mt, __shfl_xor(mt, 1));
            mt = fmaxf(mt, __shfl_xor(mt, 2));
            mt = fmaxf(mt, __shfl_xor(mt, 4));
            mt = fmaxf(mt, __shfl_xor(mt, 8));
            mnew[r]  = fmaxf(mrow[r], mt);
            alpha[r] = __expf(mrow[r] - mnew[r]);
            mrow[r]  = mnew[r];
        }
        float p[4][4];
#pragma unroll
        for (int r = 0; r < 4; ++r) {
            float lt = 0.f;
#pragma unroll
            for (int nt = 0; nt < 4; ++nt) { p[nt][r] = __expf(s[nt][r] - mnew[r]); lt += p[nt][r]; }
            lt += __shfl_xor(lt, 1);
            lt += __shfl_xor(lt, 2);
            lt += __shfl_xor(lt, 4);
            lt += __shfl_xor(lt, 8);
            lrow[r] = lrow[r]*alpha[r] + lt;
#pragma unroll
            for (int nt = 0; nt < 4; ++nt) o[nt][r] *= alpha[r];
        }

#pragma unroll
        for (int nt = 0; nt < 4; ++nt)
#pragma unroll
            for (int r = 0; r < 4; ++r)
                Pb[w][quad*4 + r][nt*16 + lx] = p[nt][r];

        bf16x8 ph[2], pl[2];
#pragma unroll
        for (int ks = 0; ks < 2; ++ks) {
            float pv[8];
            *(f32x4*)&pv[0] = *(const f32x4*)&Pb[w][lx][ks*32 + quad*8];
            *(f32x4*)&pv[4] = *(const f32x4*)&Pb[w][lx][ks*32 + quad*8 + 4];
#pragma unroll
            for (int j = 0; j < 8; ++j) {
                const unsigned ub = fbits(pv[j]);
                ph[ks][j] = (short)(ub >> 16);
                const float lof = pv[j] - bitsf(ub & 0xffff0000u);
                pl[ks][j] = (short)(fbits(lof) >> 16);
            }
        }

#pragma unroll
        for (int nt = 0; nt < 4; ++nt) {
            const int row = nt*16 + lx;
            const int base = row*64;
            const int sw = lx & 7;
            const int c0 = ((0*4 + quad) ^ sw) * 8;
            const int c1 = ((1*4 + quad) ^ sw) * 8;
            const bf16x8 vh0 = *(const bf16x8*)&VH[base + c0];
            const bf16x8 vh1 = *(const bf16x8*)&VH[base + c1];
            const bf16x8 vl0 = *(const bf16x8*)&VL[base + c0];
            const bf16x8 vl1 = *(const bf16x8*)&VL[base + c1];
            o[nt] = __builtin_amdgcn_mfma_f32_16x16x32_bf16(ph[0], vh0, o[nt], 0, 0, 0);
            o[nt] = __builtin_amdgcn_mfma_f32_16x16x32_bf16(ph[1], vh1, o[nt], 0, 0, 0);
            o[nt] = __builtin_amdgcn_mfma_f32_16x16x32_bf16(pl[0], vh0, o[nt], 0, 0, 0);
            o[nt] = __builtin_amdgcn_mfma_f32_16x16x32_bf16(pl[1], vh1, o[nt], 0, 0, 0);
            o[nt] = __builtin_amdgcn_mfma_f32_16x16x32_bf16(ph[0], vl0, o[nt], 0, 0, 0);
            o[nt] = __builtin_amdgcn_mfma_f32_16x16x32_bf16(ph[1], vl1, o[nt], 0, 0, 0);
        }

        __syncthreads();
#pragma unroll
        for (int p2 = 0; p2 < 2; ++p2) {
            *(bf16x8*)&KH[lw[p2]] = rkh[p2];
            *(bf16x8*)&KL[lw[p2]] = rkl[p2];
            *(bf16x8*)&VH[lw[p2]] = rvh[p2];
            *(bf16x8*)&VL[lw[p2]] = rvl[p2];
        }
        __syncthreads();
    }

    float inv[4];
#pragma unroll
    for (int r = 0; r < 4; ++r) inv[r] = 1.0f / lrow[r];
#pragma unroll
    for (int nt = 0; nt < 4; ++nt)
#pragma unroll
        for (int r = 0; r < 4; ++r) {
            const int t = qrow0 + quad*4 + r;
            O[(((size_t)b)*T_SEQ + t)*DM + h*HD + nt*16 + lx] = o[nt][r] * inv[r];
        }
}

// -------------------------------------------------------------------------
// Workspace (128.03 MiB, alias plan unchanged).
// -------------------------------------------------------------------------
extern "C" void kernel_launch(void* const* d_in, const int* in_sizes, int n_in,
                              void* d_out, int out_size, void* d_ws, size_t ws_size,
                              hipStream_t stream)
{
    const float* tokens = (const float*)d_in[0];
    const int*   pad    = (const int*)d_in[1];
    const float* Wqkv   = (const float*)d_in[2];
    const float* bqkv   = (const float*)d_in[3];
    const float* Wout   = (const float*)d_in[4];
    const float* bout   = (const float*)d_in[5];
    float* out = (float*)d_out;

    const size_t SZ = (size_t)8388608;
    ushort_t* U = (ushort_t*)d_ws;
    ushort_t* Qhi  = U;
    ushort_t* Qlo  = U + SZ;
    ushort_t* Khi  = U + 2*SZ;
    ushort_t* Klo  = U + 3*SZ;
    ushort_t* Vthi = U + 4*SZ;
    ushort_t* Vtlo = U + 5*SZ;
    float* MSK = (float*)(U + 6*SZ);
    float* AO  = MSK + 8192;
    ushort_t* WqkvTh = (ushort_t*)AO;
    ushort_t* WqkvTl = WqkvTh + (size_t)3*DM*DM;
    ushort_t* WoutTh = Qhi;
    ushort_t* WoutTl = Qhi + (size_t)DM*DM;

    maskprep_kernel<<<dim3(BATCH), dim3(256), 0, stream>>>(pad, MSK);
    transpose_split_kernel<<<dim3(48, 16), dim3(256), 0, stream>>>(
        Wqkv, WqkvTh, WqkvTl, DM, 3*DM);
    mfma_gemm_kernel<1><<<dim3(24, 64), dim3(256), 0, stream>>>(
        tokens, WqkvTh, WqkvTl, bqkv, nullptr,
        Qhi, Qlo, Khi, Klo, Vthi, Vtlo, BATCH*T_SEQ, 3*DM, DM);
    attn_mfma_kernel<<<dim3(2048), dim3(256), 0, stream>>>(
        Qhi, Qlo, Khi, Klo, Vthi, Vtlo, MSK, AO);
    transpose_split_kernel<<<dim3(16, 16), dim3(256), 0, stream>>>(
        Wout, WoutTh, WoutTl, DM, DM);
    mfma_gemm_kernel<0><<<dim3(8, 64), dim3(256), 0, stream>>>(
        AO, WoutTh, WoutTl, bout, out,
        nullptr, nullptr, nullptr, nullptr, nullptr, nullptr, BATCH*T_SEQ, DM, DM);
}

// Round 7
// 1087.237 us; speedup vs baseline: 1.7352x; 1.0570x over previous
//
#include <hip/hip_runtime.h>
#include <cmath>

#define T_SEQ 2048
#define NH    16
#define HD    64
#define DM    1024
#define BATCH 4

typedef __attribute__((ext_vector_type(8))) short bf16x8;
typedef __attribute__((ext_vector_type(4))) float f32x4;
typedef unsigned short ushort_t;

__device__ __forceinline__ unsigned short f2bf(float x) {   // rne fp32->bf16
    union { float f; unsigned u; } v; v.f = x;
    unsigned r = v.u + 0x7fffu + ((v.u >> 16) & 1u);
    return (unsigned short)(r >> 16);
}
__device__ __forceinline__ float bf2f(unsigned short h) {
    union { unsigned u; float f; } v; v.u = ((unsigned)h) << 16;
    return v.f;
}
__device__ __forceinline__ unsigned fbits(float x) {
    union { float f; unsigned u; } v; v.f = x; return v.u;
}
__device__ __forceinline__ float bitsf(unsigned x) {
    union { unsigned u; float f; } v; v.u = x; return v.f;
}

// async global->LDS DMA, 16 B per lane. LDS dest = wave-uniform base + lane*16;
// we pass each lane's own dest (== that address) via AS(3) offset cast.
__device__ __forceinline__ void dma16(const void* g, const void* l) {
    __builtin_amdgcn_global_load_lds(
        (const __attribute__((address_space(1))) unsigned int*)(unsigned long long)g,
        (__attribute__((address_space(3))) unsigned int*)(unsigned int)(unsigned long long)l,
        16, 0, 0);
}

// -------------------------------------------------------------------------
// Kernel 1: mask prep (unchanged).
// -------------------------------------------------------------------------
__global__ void maskprep_kernel(const int* __restrict__ pad, float* __restrict__ valid)
{
    __shared__ int sall[256];
    const int b = blockIdx.x;
    const int t = threadIdx.x;
    int allp = 1;
    for (int i = t; i < T_SEQ; i += 256) allp &= (pad[b*T_SEQ + i] != 0) ? 1 : 0;
    sall[t] = allp;
    __syncthreads();
    for (int s = 128; s > 0; s >>= 1) {
        if (t < s) sall[t] &= sall[t + s];
        __syncthreads();
    }
    const int ap = sall[0];
    for (int i = t; i < T_SEQ; i += 256) {
        const int p = (pad[b*T_SEQ + i] != 0) ? 1 : 0;
        valid[b*T_SEQ + i] = (p && !ap) ? 0.0f : 1.0f;
    }
}

// -------------------------------------------------------------------------
// Kernel 2: weight transpose+split (unchanged). W[K][N] -> Th/Tl[N][K].
// -------------------------------------------------------------------------
__global__ __launch_bounds__(256)
void transpose_split_kernel(const float* __restrict__ W,
                            ushort_t* __restrict__ Th, ushort_t* __restrict__ Tl,
                            int K, int N)
{
    __shared__ float T[64][68];
    const int tid = threadIdx.x;
    const int n0 = blockIdx.x * 64;
    const int k0 = blockIdx.y * 64;
#pragma unroll
    for (int i = 0; i < 4; ++i) {
        const int kr = (tid >> 4) + i*16;
        const int nc = (tid & 15) * 4;
        const float4 v = *(const float4*)&W[(size_t)(k0 + kr)*N + n0 + nc];
        T[nc+0][kr] = v.x; T[nc+1][kr] = v.y; T[nc+2][kr] = v.z; T[nc+3][kr] = v.w;
    }
    __syncthreads();
#pragma unroll
    for (int i = 0; i < 4; ++i) {
        const int nr = (tid >> 4) + i*16;
        const int kc = (tid & 15) * 4;
        ushort_t h[4], l[4];
#pragma unroll
        for (int j = 0; j < 4; ++j) {
            const float x = T[nr][kc + j];
            h[j] = f2bf(x);
            l[j] = f2bf(x - bf2f(h[j]));
        }
        const size_t off = (size_t)(n0 + nr)*K + k0 + kc;
        *(short4*)&Th[off] = make_short4(h[0], h[1], h[2], h[3]);
        *(short4*)&Tl[off] = make_short4(l[0], l[1], l[2], l[3]);
    }
}

// -------------------------------------------------------------------------
// Kernel 2b: row-major fp32 -> bf16 hi/lo split (trunc hi + rne lo, same
// formula as the old in-loop staging). Memory-bound, ~13 us for 32 MB.
// -------------------------------------------------------------------------
__global__ __launch_bounds__(256)
void split_kernel(const float* __restrict__ X,
                  ushort_t* __restrict__ H, ushort_t* __restrict__ L)
{
    const int i = blockIdx.x * 256 + threadIdx.x;     // float4 index
    const float4 v = ((const float4*)X)[i];
    const float x[4] = {v.x, v.y, v.z, v.w};
    ushort_t h[4], l[4];
#pragma unroll
    for (int j = 0; j < 4; ++j) {
        const unsigned u = fbits(x[j]);
        h[j] = (ushort_t)(u >> 16);
        l[j] = f2bf(x[j] - bitsf(u & 0xffff0000u));
    }
    *(short4*)&H[(size_t)i*4] = make_short4(h[0], h[1], h[2], h[3]);
    *(short4*)&L[(size_t)i*4] = make_short4(l[0], l[1], l[2], l[3]);
}

// -------------------------------------------------------------------------
// Kernel 3/5: split-bf16 MFMA GEMM, 128x128xBK32, ZERO-VGPR staging via
// global_load_lds (m97 pattern). All four operands pre-split bf16 [row][k].
// LDS: Ah|Al|Bh|Bl tiles, each [128][32] bf16 = 8 KB, unpadded 64 B rows
// (bank-uniform for the 16B frag pattern). K-loop per iter:
//   barrier (drains DMA for tile kk) -> 16x ds_read_b128 frags -> barrier
//   -> issue 8 DMA for kk+32 -> 48 MFMAs (ah*bh + ah*bl + al*bh).
// Epilogue unchanged from R6 (LDS-staged coalesced stores).
// -------------------------------------------------------------------------
template<int EPI>
__global__ __launch_bounds__(256, 2)
void mfma_gemm_kernel(const ushort_t* __restrict__ Ath, const ushort_t* __restrict__ Atl,
                      const ushort_t* __restrict__ BTh, const ushort_t* __restrict__ BTl,
                      const float* __restrict__ bias,
                      float* __restrict__ O0,
                      ushort_t* __restrict__ Qhi, ushort_t* __restrict__ Qlo,
                      ushort_t* __restrict__ Khi, ushort_t* __restrict__ Klo,
                      ushort_t* __restrict__ Vthi, ushort_t* __restrict__ Vtlo,
                      int M, int N, int K)
{
    __shared__ __align__(16) char smem[34816];   // 32 KB tiles / 34 KB epi union
    char* smA  = smem;            // Ah: 8 KB
    char* smAl = smem + 8192;     // Al
    char* smBh = smem + 16384;    // Bh
    char* smBl = smem + 24576;    // Bl

    const int tid  = threadIdx.x;
    const int w    = tid >> 6;
    const int ln   = tid & 63;
    const int lx   = ln & 15;
    const int quad = ln >> 4;
    const int mw   = (w >> 1) * 64;
    const int nw   = (w & 1) * 64;
    const int m0   = blockIdx.y * 128;
    const int n0   = blockIdx.x * 128;

    // DMA geometry: per array, 8 KB tile = 8 wave-instructions (2 per wave).
    // instr j: lane ln covers row (w*32 + j*16 + ln/4), 16B chunk (ln&3).
    const int drow  = w*32 + (ln >> 2);
    const size_t ga0 = (size_t)(m0 + drow)*K + (ln & 3)*8;       // j=0, +16*K for j=1
    const size_t gb0 = (size_t)(n0 + drow)*K + (ln & 3)*8;
    const int lds0   = (w*128 + ln)*16;                          // j=0 byte off, +1024 j=1

#define ISSUE_DMA(kk) do {                                               \
        dma16(Ath + ga0 + (kk),        smA  + lds0);                     \
        dma16(Ath + ga0 + 16*K + (kk), smA  + lds0 + 1024);              \
        dma16(Atl + ga0 + (kk),        smAl + lds0);                     \
        dma16(Atl + ga0 + 16*K + (kk), smAl + lds0 + 1024);              \
        dma16(BTh + gb0 + (kk),        smBh + lds0);                     \
        dma16(BTh + gb0 + 16*K + (kk), smBh + lds0 + 1024);              \
        dma16(BTl + gb0 + (kk),        smBl + lds0);                     \
        dma16(BTl + gb0 + 16*K + (kk), smBl + lds0 + 1024);              \
    } while (0)

    f32x4 acc[4][4];
#pragma unroll
    for (int mt = 0; mt < 4; ++mt)
#pragma unroll
        for (int nt = 0; nt < 4; ++nt) acc[mt][nt] = (f32x4){0.f,0.f,0.f,0.f};

    ISSUE_DMA(0);

    for (int kk = 0; kk < K; kk += 32) {
        __syncthreads();                       // DMA for tile kk landed
        bf16x8 afh[4], afl[4], bfh[4], bfl[4];
#pragma unroll
        for (int mt = 0; mt < 4; ++mt) {
            const int off = (mw + mt*16 + lx)*64 + quad*16;
            afh[mt] = *(const bf16x8*)(smA  + off);
            afl[mt] = *(const bf16x8*)(smAl + off);
        }
#pragma unroll
        for (int nt = 0; nt < 4; ++nt) {
            const int off = (nw + nt*16 + lx)*64 + quad*16;
            bfh[nt] = *(const bf16x8*)(smBh + off);
            bfl[nt] = *(const bf16x8*)(smBl + off);
        }
        __syncthreads();                       // all reads done; tile reusable
        if (kk + 32 < K) ISSUE_DMA(kk + 32);   // async while we MFMA

#pragma unroll
        for (int mt = 0; mt < 4; ++mt)
#pragma unroll
            for (int nt = 0; nt < 4; ++nt) {
                acc[mt][nt] = __builtin_amdgcn_mfma_f32_16x16x32_bf16(afh[mt], bfh[nt], acc[mt][nt], 0, 0, 0);
                acc[mt][nt] = __builtin_amdgcn_mfma_f32_16x16x32_bf16(afh[mt], bfl[nt], acc[mt][nt], 0, 0, 0);
                acc[mt][nt] = __builtin_amdgcn_mfma_f32_16x16x32_bf16(afl[mt], bfh[nt], acc[mt][nt], 0, 0, 0);
            }
    }
#undef ISSUE_DMA

    // ---------------- epilogue (R6 logic, verified) ----------------
    if (EPI == 0) {
#pragma unroll
        for (int nt = 0; nt < 4; ++nt) {
            const int n = n0 + nw + nt*16 + lx;
#pragma unroll
            for (int mt = 0; mt < 4; ++mt)
#pragma unroll
                for (int r = 0; r < 4; ++r) {
                    const int m = m0 + mw + mt*16 + quad*4 + r;
                    O0[(size_t)m*N + n] = acc[mt][nt][r] + bias[n];
                }
        }
    } else {
        const int which = n0 >> 10;           // block-uniform: 0=q 1=k 2=v
        const int hbase = (n0 & 1023) >> 6;
        const int b     = m0 >> 11;
        const int t0    = m0 & 2047;
        float* Ct = (float*)smem;             // Q/K: [64][132]; V: [128][68]
        const float ssign = (lx & 1) ? 1.0f : -1.0f;

        for (int mhalf = 0; mhalf < 2; ++mhalf) {
            __syncthreads();
            if (mw == mhalf*64) {
                if (which < 2) {
#pragma unroll
                    for (int nt = 0; nt < 4; ++nt) {
                        const int nl = nw + nt*16 + lx;
                        const int d  = nl & 63;
                        const float bn = bias[n0 + nl];
                        const float freq = expf(-(float)(d >> 1) * 0.28782313662425575f);
#pragma unroll
                        for (int mt = 0; mt < 4; ++mt)
#pragma unroll
                            for (int r = 0; r < 4; ++r) {
                                const int ml = mt*16 + quad*4 + r;
                                const int t  = t0 + mhalf*64 + ml;
                                float res = acc[mt][nt][r] + bn;
                                const float ang = (float)t * freq;
                                const float sn = sinf(ang), cs = cosf(ang);
                                const float prt = __shfl_xor(res, 1);
                                res = res*cs + ssign*prt*sn;
                                if (which == 0) res *= 0.125f;
                                Ct[ml*132 + nl] = res;
                            }
                    }
                } else {
#pragma unroll
                    for (int nt = 0; nt < 4; ++nt) {
                        const int nl = nw + nt*16 + lx;
                        const float bn = bias[n0 + nl];
#pragma unroll
                        for (int mt = 0; mt < 4; ++mt)
#pragma unroll
                            for (int r = 0; r < 4; ++r) {
                                const int ml = mt*16 + quad*4 + r;
                                Ct[nl*68 + ml] = acc[mt][nt][r] + bn;
                            }
                    }
                }
            }
            __syncthreads();
            if (which < 2) {
                ushort_t* dH = which ? Khi : Qhi;
                ushort_t* dL = which ? Klo : Qlo;
#pragma unroll
                for (int ui = 0; ui < 4; ++ui) {
                    const int u  = w*4 + ui;
                    const int hl = u >> 3, titer = u & 7;
                    const int tl = titer*8 + (ln >> 3);
                    const int dg = (ln & 7) * 8;
                    const float* src = &Ct[tl*132 + hl*64 + dg];
                    float v[8];
                    *(f32x4*)&v[0] = *(const f32x4*)src;
                    *(f32x4*)&v[4] = *(const f32x4*)(src + 4);
                    bf16x8 h8, l8;
#pragma unroll
                    for (int j = 0; j < 8; ++j) {
                        const unsigned u32 = fbits(v[j]);
                        h8[j] = (short)(u32 >> 16);
                        l8[j] = (short)f2bf(v[j] - bitsf(u32 & 0xffff0000u));
                    }
                    const int t  = t0 + mhalf*64 + tl;
                    const int bh = b*NH + hbase + hl;
                    const size_t off = (((size_t)bh)*T_SEQ + t)*64 + dg;
                    *(bf16x8*)&dH[off] = h8;
                    *(bf16x8*)&dL[off] = l8;
                }
            } else {
#pragma unroll
                for (int ui = 0; ui < 4; ++ui) {
                    const int u  = w*4 + ui;
                    const int nr = u*8 + (ln >> 3);
                    const int d  = nr & 63, hl = nr >> 6;
                    const int tg = (ln & 7) * 8;
                    const float* src = &Ct[nr*68 + tg];
                    float v[8];
                    *(f32x4*)&v[0] = *(const f32x4*)src;
                    *(f32x4*)&v[4] = *(const f32x4*)(src + 4);
                    bf16x8 h8, l8;
#pragma unroll
                    for (int j = 0; j < 8; ++j) {
                        const unsigned u32 = fbits(v[j]);
                        h8[j] = (short)(u32 >> 16);
                        l8[j] = (short)f2bf(v[j] - bitsf(u32 & 0xffff0000u));
                    }
                    const int bh = b*NH + hbase + hl;
                    const size_t off = (((size_t)bh)*HD + d)*T_SEQ + t0 + mhalf*64 + tg;
                    *(bf16x8*)&Vthi[off] = h8;
                    *(bf16x8*)&Vtlo[off] = l8;
                }
            }
        }
    }
}

// -------------------------------------------------------------------------
// Kernel 4: flash attention (unchanged — verified, WRITE_SIZE clean).
// -------------------------------------------------------------------------
__global__ __launch_bounds__(256, 2)
void attn_mfma_kernel(const ushort_t* __restrict__ Qhi, const ushort_t* __restrict__ Qlo,
                      const ushort_t* __restrict__ Khi, const ushort_t* __restrict__ Klo,
                      const ushort_t* __restrict__ Vthi, const ushort_t* __restrict__ Vtlo,
                      const float* __restrict__ valid, float* __restrict__ O)
{
    __shared__ ushort_t KH[64*64];
    __shared__ ushort_t KL[64*64];
    __shared__ ushort_t VH[64*64];
    __shared__ ushort_t VL[64*64];
    __shared__ float Pb[4][16][68];

    const int tid  = threadIdx.x;
    const int w    = tid >> 6;
    const int ln   = tid & 63;
    const int lx   = ln & 15;
    const int quad = ln >> 4;

    const int id = blockIdx.x;
    const int qt = (id >> 3) & 31;
    const int bh = ((id >> 8) << 3) | (id & 7);
    const int b  = bh >> 4;
    const int h  = bh & 15;
    const int qrow0 = qt*64 + w*16;

    bf16x8 qh[2], ql[2];
    {
        const size_t qoff = (((size_t)bh)*T_SEQ + qrow0 + lx)*HD + quad*8;
        qh[0] = *(const bf16x8*)&Qhi[qoff];
        qh[1] = *(const bf16x8*)&Qhi[qoff + 32];
        ql[0] = *(const bf16x8*)&Qlo[qoff];
        ql[1] = *(const bf16x8*)&Qlo[qoff + 32];
    }

    const int srow0 = w*16 + (ln >> 3);
    const int sch   = ln & 7;
    const size_t kg0 = ((size_t)bh*T_SEQ + srow0)*HD + sch*8;
    const size_t vg0 = ((size_t)bh*HD + srow0)*T_SEQ + sch*8;
    int lw[2];
#pragma unroll
    for (int p = 0; p < 2; ++p) {
        const int r = srow0 + p*8;
        lw[p] = r*64 + ((sch ^ (r & 7)) * 8);
    }

    const float* vrow = valid + (size_t)b*T_SEQ + lx;

    f32x4 o[4];
#pragma unroll
    for (int nt = 0; nt < 4; ++nt) o[nt] = (f32x4){0.f, 0.f, 0.f, 0.f};
    float mrow[4] = {-INFINITY, -INFINITY, -INFINITY, -INFINITY};
    float lrow[4] = {0.f, 0.f, 0.f, 0.f};

    bf16x8 rkh[2], rkl[2], rvh[2], rvl[2];
#pragma unroll
    for (int p = 0; p < 2; ++p) {
        rkh[p] = *(const bf16x8*)&Khi [kg0 + p*8*HD];
        rkl[p] = *(const bf16x8*)&Klo [kg0 + p*8*HD];
        rvh[p] = *(const bf16x8*)&Vthi[vg0 + p*8*T_SEQ];
        rvl[p] = *(const bf16x8*)&Vtlo[vg0 + p*8*T_SEQ];
    }
#pragma unroll
    for (int p = 0; p < 2; ++p) {
        *(bf16x8*)&KH[lw[p]] = rkh[p];
        *(bf16x8*)&KL[lw[p]] = rkl[p];
        *(bf16x8*)&VH[lw[p]] = rvh[p];
        *(bf16x8*)&VL[lw[p]] = rvl[p];
    }
    __syncthreads();

    for (int kt = 0; kt < T_SEQ/64; ++kt) {
        const int ktn = (kt+1 < T_SEQ/64) ? kt+1 : kt;
#pragma unroll
        for (int p = 0; p < 2; ++p) {
            rkh[p] = *(const bf16x8*)&Khi [kg0 + (size_t)ktn*64*HD + p*8*HD];
            rkl[p] = *(const bf16x8*)&Klo [kg0 + (size_t)ktn*64*HD + p*8*HD];
            rvh[p] = *(const bf16x8*)&Vthi[vg0 + ktn*64 + p*8*T_SEQ];
            rvl[p] = *(const bf16x8*)&Vtlo[vg0 + ktn*64 + p*8*T_SEQ];
        }
        float mk[4];
#pragma unroll
        for (int nt = 0; nt < 4; ++nt) mk[nt] = vrow[kt*64 + nt*16];

        f32x4 s[4];
#pragma unroll
        for (int nt = 0; nt < 4; ++nt) {
            const int row = nt*16 + lx;
            const int base = row*64;
            const int sw = lx & 7;
            const int c0 = ((0*4 + quad) ^ sw) * 8;
            const int c1 = ((1*4 + quad) ^ sw) * 8;
            const bf16x8 kh0 = *(const bf16x8*)&KH[base + c0];
            const bf16x8 kh1 = *(const bf16x8*)&KH[base + c1];
            const bf16x8 kl0 = *(const bf16x8*)&KL[base + c0];
            const bf16x8 kl1 = *(const bf16x8*)&KL[base + c1];
            s[nt] = (f32x4){0.f, 0.f, 0.f, 0.f};
            s[nt] = __builtin_amdgcn_mfma_f32_16x16x32_bf16(qh[0], kh0, s[nt], 0, 0, 0);
            s[nt] = __builtin_amdgcn_mfma_f32_16x16x32_bf16(qh[1], kh1, s[nt], 0, 0, 0);
            s[nt] = __builtin_amdgcn_mfma_f32_16x16x32_bf16(ql[0], kh0, s[nt], 0, 0, 0);
            s[nt] = __builtin_amdgcn_mfma_f32_16x16x32_bf16(ql[1], kh1, s[nt], 0, 0, 0);
            s[nt] = __builtin_amdgcn_mfma_f32_16x16x32_bf16(qh[0], kl0, s[nt], 0, 0, 0);
            s[nt] = __builtin_amdgcn_mfma_f32_16x16x32_bf16(qh[1], kl1, s[nt], 0, 0, 0);
        }

#pragma unroll
        for (int nt = 0; nt < 4; ++nt) {
            const bool ok = mk[nt] > 0.5f;
#pragma unroll
            for (int r = 0; r < 4; ++r) s[nt][r] = ok ? s[nt][r] : -1e30f;
        }

        float alpha[4], mnew[4];
#pragma unroll
        for (int r = 0; r < 4; ++r) {
            float mt = fmaxf(fmaxf(s[0][r], s[1][r]), fmaxf(s[2][r], s[3][r]));
            mt = fmaxf(mt, __shfl_xor(mt, 1));
            mt = fmaxf(mt, __shfl_xor(mt, 2));
            mt = fmaxf(mt, __shfl_xor(mt, 4));
            mt = fmaxf(mt, __shfl_xor(mt, 8));
            mnew[r]  = fmaxf(mrow[r], mt);
            alpha[r] = __expf(mrow[r] - mnew[r]);
            mrow[r]  = mnew[r];
        }
        float p[4][4];
#pragma unroll
        for (int r = 0; r < 4; ++r) {
            float lt = 0.f;
#pragma unroll
            for (int nt = 0; nt < 4; ++nt) { p[nt][r] = __expf(s[nt][r] - mnew[r]); lt += p[nt][r]; }
            lt += __shfl_xor(lt, 1);
            lt += __shfl_xor(lt, 2);
            lt += __shfl_xor(lt, 4);
            lt += __shfl_xor(lt, 8);
            lrow[r] = lrow[r]*alpha[r] + lt;
#pragma unroll
            for (int nt = 0; nt < 4; ++nt) o[nt][r] *= alpha[r];
        }

#pragma unroll
        for (int nt = 0; nt < 4; ++nt)
#pragma unroll
            for (int r = 0; r < 4; ++r)
                Pb[w][quad*4 + r][nt*16 + lx] = p[nt][r];

        bf16x8 ph[2], pl[2];
#pragma unroll
        for (int ks = 0; ks < 2; ++ks) {
            float pv[8];
            *(f32x4*)&pv[0] = *(const f32x4*)&Pb[w][lx][ks*32 + quad*8];
            *(f32x4*)&pv[4] = *(const f32x4*)&Pb[w][lx][ks*32 + quad*8 + 4];
#pragma unroll
            for (int j = 0; j < 8; ++j) {
                const unsigned ub = fbits(pv[j]);
                ph[ks][j] = (short)(ub >> 16);
                const float lof = pv[j] - bitsf(ub & 0xffff0000u);
                pl[ks][j] = (short)(fbits(lof) >> 16);
            }
        }

#pragma unroll
        for (int nt = 0; nt < 4; ++nt) {
            const int row = nt*16 + lx;
            const int base = row*64;
            const int sw = lx & 7;
            const int c0 = ((0*4 + quad) ^ sw) * 8;
            const int c1 = ((1*4 + quad) ^ sw) * 8;
            const bf16x8 vh0 = *(const bf16x8*)&VH[base + c0];
            const bf16x8 vh1 = *(const bf16x8*)&VH[base + c1];
            const bf16x8 vl0 = *(const bf16x8*)&VL[base + c0];
            const bf16x8 vl1 = *(const bf16x8*)&VL[base + c1];
            o[nt] = __builtin_amdgcn_mfma_f32_16x16x32_bf16(ph[0], vh0, o[nt], 0, 0, 0);
            o[nt] = __builtin_amdgcn_mfma_f32_16x16x32_bf16(ph[1], vh1, o[nt], 0, 0, 0);
            o[nt] = __builtin_amdgcn_mfma_f32_16x16x32_bf16(pl[0], vh0, o[nt], 0, 0, 0);
            o[nt] = __builtin_amdgcn_mfma_f32_16x16x32_bf16(pl[1], vh1, o[nt], 0, 0, 0);
            o[nt] = __builtin_amdgcn_mfma_f32_16x16x32_bf16(ph[0], vl0, o[nt], 0, 0, 0);
            o[nt] = __builtin_amdgcn_mfma_f32_16x16x32_bf16(ph[1], vl1, o[nt], 0, 0, 0);
        }

        __syncthreads();
#pragma unroll
        for (int p2 = 0; p2 < 2; ++p2) {
            *(bf16x8*)&KH[lw[p2]] = rkh[p2];
            *(bf16x8*)&KL[lw[p2]] = rkl[p2];
            *(bf16x8*)&VH[lw[p2]] = rvh[p2];
            *(bf16x8*)&VL[lw[p2]] = rvl[p2];
        }
        __syncthreads();
    }

    float inv[4];
#pragma unroll
    for (int r = 0; r < 4; ++r) inv[r] = 1.0f / lrow[r];
#pragma unroll
    for (int nt = 0; nt < 4; ++nt)
#pragma unroll
        for (int r = 0; r < 4; ++r) {
            const int t = qrow0 + quad*4 + r;
            O[(((size_t)b)*T_SEQ + t)*DM + h*HD + nt*16 + lx] = o[nt][r] * inv[r];
        }
}

// -------------------------------------------------------------------------
// Memory plan (d_ws 128.03 MiB + d_out 32 MiB as scratch):
//   d_ws: Qhi Qlo Khi Klo Vthi Vtlo (6x16 MiB) | MSK 32 KiB |
//         AO(32 MiB) union WqkvTh/Tl(12 MiB, dead before attention)
//   d_out: TokH/TokL (32 MiB) — dead after QKV GEMM, final GEMM overwrites
//   AOh/AOl  <- Qhi/Qlo regions (dead after attention)
//   WoutTh/Tl <- Khi region (dead after attention)
// -------------------------------------------------------------------------
extern "C" void kernel_launch(void* const* d_in, const int* in_sizes, int n_in,
                              void* d_out, int out_size, void* d_ws, size_t ws_size,
                              hipStream_t stream)
{
    const float* tokens = (const float*)d_in[0];
    const int*   pad    = (const int*)d_in[1];
    const float* Wqkv   = (const float*)d_in[2];
    const float* bqkv   = (const float*)d_in[3];
    const float* Wout   = (const float*)d_in[4];
    const float* bout   = (const float*)d_in[5];
    float* out = (float*)d_out;

    const size_t SZ = (size_t)8388608;
    ushort_t* U = (ushort_t*)d_ws;
    ushort_t* Qhi  = U;
    ushort_t* Qlo  = U + SZ;
    ushort_t* Khi  = U + 2*SZ;
    ushort_t* Klo  = U + 3*SZ;
    ushort_t* Vthi = U + 4*SZ;
    ushort_t* Vtlo = U + 5*SZ;
    float* MSK = (float*)(U + 6*SZ);
    float* AO  = MSK + 8192;
    ushort_t* WqkvTh = (ushort_t*)AO;
    ushort_t* WqkvTl = WqkvTh + (size_t)3*DM*DM;
    ushort_t* TokH = (ushort_t*)d_out;             // scratch in d_out
    ushort_t* TokL = TokH + SZ;
    ushort_t* AOh  = Qhi;                          // reuse after attention
    ushort_t* AOl  = Qlo;
    ushort_t* WoutTh = Khi;
    ushort_t* WoutTl = Khi + (size_t)DM*DM;

    maskprep_kernel<<<dim3(BATCH), dim3(256), 0, stream>>>(pad, MSK);
    split_kernel<<<dim3(8192), dim3(256), 0, stream>>>(tokens, TokH, TokL);
    transpose_split_kernel<<<dim3(48, 16), dim3(256), 0, stream>>>(
        Wqkv, WqkvTh, WqkvTl, DM, 3*DM);
    mfma_gemm_kernel<1><<<dim3(24, 64), dim3(256), 0, stream>>>(
        TokH, TokL, WqkvTh, WqkvTl, bqkv, nullptr,
        Qhi, Qlo, Khi, Klo, Vthi, Vtlo, BATCH*T_SEQ, 3*DM, DM);
    attn_mfma_kernel<<<dim3(2048), dim3(256), 0, stream>>>(
        Qhi, Qlo, Khi, Klo, Vthi, Vtlo, MSK, AO);
    split_kernel<<<dim3(8192), dim3(256), 0, stream>>>(AO, AOh, AOl);
    transpose_split_kernel<<<dim3(16, 16), dim3(256), 0, stream>>>(
        Wout, WoutTh, WoutTl, DM, DM);
    mfma_gemm_kernel<0><<<dim3(8, 64), dim3(256), 0, stream>>>(
        AOh, AOl, WoutTh, WoutTl, bout, out,
        nullptr, nullptr, nullptr, nullptr, nullptr, nullptr, BATCH*T_SEQ, DM, DM);
}